// Round 10
// baseline (249.772 us; speedup 1.0000x reference)
//
#include <hip/hip_runtime.h>
#include <hip/hip_bf16.h>

// Problem constants (fixed by reference)
#define N_NODES 20000
#define NUM_DRUGS 2048
#define N_PROT (N_NODES - NUM_DRUGS)
#define NUM_DPI 200000
#define E2 400000          // 2*NUM_DPI directed edges
#define CDIM 256           // IN_C == EMB == 256
#define HID 512
#define N_CL 8
#define BATCH 16384
#define HN 8192            // H cols = 8 experts x 2 halves x 512

#define STRD 32            // drug counter padding (ints) = 1 line per counter
#define STRP 16            // protein counter padding
#define ELLD 192           // drug ELL stride (mean deg 97.7, +9.5 sigma)
#define ELLP 48            // protein ELL stride (mean deg 11.1, +11 sigma)

// fused-prep block ranges (fill FIRST: atomic-latency-bound, starts early and
// hides under the bandwidth-bound splits/transposes)
#define NB_FILL 782        // ELL fill: 200000 / 256
#define NB_T64 512         // W1 transpose: 4 x 8 x 16
#define NB_TWG 32          // Wg1/Wg2 transpose: 4 x 4 x 2
#define NB_SPLIT 20000     // x split: 5.12M / 256

// node-GEMM tiling (BM=64): 313 row tiles; XCD-paired grid of 640 (8 x 80)
// R9 BUG FIX: was 632 (8x79) — 79 slots cannot tile 40 panels x 2 halves, so
// 7 output tiles (panel 39 of each XCD, col-half 1) were never computed.
#define MT_NODE 313
#define NB_GNODE 640       // 8 XCDs x 80 slots (40 row-panels x 2 col-halves; 14 idle)

// aggregate1 grid split
#define NB_AGG_D NUM_DRUGS              // 1 block per drug (4 waves)
#define NB_AGG_P ((N_PROT + 3) / 4)     // 4 proteins per block (1 wave each)

typedef __attribute__((ext_vector_type(8))) short short8;   // 8 bf16 (MFMA A/B frag)
typedef __attribute__((ext_vector_type(4))) float floatx4;  // MFMA C/D frag

__device__ inline unsigned short f2bf(float f) {
    unsigned u = __float_as_uint(f);
    u += 0x7fff + ((u >> 16) & 1);   // RNE
    return (unsigned short)(u >> 16);
}
__device__ inline float bf2f(unsigned short h) {
    return __uint_as_float((unsigned)h << 16);
}
__device__ inline void split2(float v, unsigned short& h, unsigned short& l) {
    h = f2bf(v);
    l = f2bf(v - bf2f(h));
}
__device__ inline void gload16(const void* g, void* l) {
    __builtin_amdgcn_global_load_lds(
        (const __attribute__((address_space(1))) void*)g,
        (__attribute__((address_space(3))) void*)l, 16, 0, 0);
}
__device__ inline float4 f4fma(float4 v, float s, float4 a) {
    a.x = fmaf(v.x, s, a.x); a.y = fmaf(v.y, s, a.y);
    a.z = fmaf(v.z, s, a.z); a.w = fmaf(v.w, s, a.w);
    return a;
}
__device__ inline float4 bf4(const unsigned short* p) {
    ushort4 q = *(const ushort4*)p;
    return make_float4(bf2f(q.x), bf2f(q.y), bf2f(q.z), bf2f(q.w));
}

// ---------------------------------------------------------------------------
// counter zeroing (tiny dispatch)
__global__ void zero_counts(int* cur_d, int* cur_p) {
    int i = blockIdx.x * blockDim.x + threadIdx.x;
    if (i < N_NODES) cur_p[i * STRP] = 0;
    if (i < NUM_DRUGS) cur_d[i * STRD] = 0;
}

// ---------------------------------------------------------------------------
// Fused prep: ELL fill | W1 transpose-split | Wg1/Wg2 transpose-split |
// x split. Counters are zeroed by the preceding zero_counts dispatch
// (stream-ordered), so the fill range runs concurrently with the rest — its
// ~6us of atomic latency hides under the bandwidth-bound block ranges.
__global__ __launch_bounds__(256) void prep_all(
        const int* __restrict__ ei, int* __restrict__ cur_d,
        int* __restrict__ adj_drug, int* __restrict__ cur_p,
        int* __restrict__ adj_prot,
        const float* __restrict__ x, unsigned short* __restrict__ xhi,
        unsigned short* __restrict__ xlo,
        const float* __restrict__ Wg1, const float* __restrict__ Wg2,
        unsigned short* __restrict__ wg1Th, unsigned short* __restrict__ wg1Tl,
        unsigned short* __restrict__ wg2Th, unsigned short* __restrict__ wg2Tl,
        const float* __restrict__ W1, unsigned short* __restrict__ W1Th,
        unsigned short* __restrict__ W1Tl) {
    __shared__ float ld[64 * 65];
    int b = blockIdx.x;
    int t = threadIdx.x;
    int tx = t & 63, ty = t >> 6;
    if (b < NB_FILL) {
        int e = b * 256 + t;
        if (e < NUM_DPI) {
            int d = ei[e];
            int p = ei[E2 + e];
            int posd = atomicAdd(&cur_d[d * STRD], 1);
            int posp = atomicAdd(&cur_p[p * STRP], 1);
            if (posd < ELLD) adj_drug[d * ELLD + posd] = p;   // clamp
            if (posp < ELLP) adj_prot[(size_t)p * ELLP + posp] = d;
        }
        return;
    }
    b -= NB_FILL;
    if (b < NB_T64) {
        // W1 [16 slabs][256][512] -> W1cat^T [8192][256] split bf16
        int m = b >> 5;
        int k0 = (b & 3) * 64, n0 = ((b >> 2) & 7) * 64;
        const float* Wm = W1 + (size_t)m * CDIM * HID;
#pragma unroll
        for (int rr = 0; rr < 16; rr++) {
            int kl = rr * 4 + ty;
            ld[tx * 65 + kl] = Wm[(size_t)(k0 + kl) * HID + n0 + tx];
        }
        __syncthreads();
        size_t obase = (size_t)m * HID * CDIM;
#pragma unroll
        for (int rr = 0; rr < 16; rr++) {
            int nl = rr * 4 + ty;
            float v = ld[nl * 65 + tx];
            unsigned short h, l;
            split2(v, h, l);
            size_t o = obase + (size_t)(n0 + nl) * CDIM + k0 + tx;
            W1Th[o] = h;
            W1Tl[o] = l;
        }
        return;
    }
    b -= NB_T64;
    if (b < NB_TWG) {
        // Wg1/Wg2 [256][256] -> transposed split bf16
        const float* W = (b >> 4) ? Wg2 : Wg1;
        unsigned short* hi = (b >> 4) ? wg2Th : wg1Th;
        unsigned short* lo = (b >> 4) ? wg2Tl : wg1Tl;
        int k0 = (b & 3) * 64, n0 = ((b >> 2) & 3) * 64;
#pragma unroll
        for (int rr = 0; rr < 16; rr++) {
            int kl = rr * 4 + ty;
            ld[tx * 65 + kl] = W[(size_t)(k0 + kl) * CDIM + n0 + tx];
        }
        __syncthreads();
#pragma unroll
        for (int rr = 0; rr < 16; rr++) {
            int nl = rr * 4 + ty;
            float v = ld[nl * 65 + tx];
            unsigned short h, l;
            split2(v, h, l);
            size_t o = (size_t)(n0 + nl) * CDIM + k0 + tx;
            hi[o] = h;
            lo[o] = l;
        }
        return;
    }
    b -= NB_TWG;
    {   // x split: exactly NB_SPLIT blocks cover 5.12M elems
        int i = b * 256 + t;
        unsigned short h, l;
        split2(x[i], h, l);
        xhi[i] = h;
        xlo[i] = l;
    }
}

// ---------------------------------------------------------------------------
// split-bf16 MFMA GEMM: C[M,N] = A[M,K] @ B[K,N], B passed as B^T ([N][K]).
// Row-major XOR-swizzled LDS; fp32 (C) and/or bf16 (Cbf) outputs, each optional.
// 2-phase prefetch, double-buffered LDS, one vmcnt(0)+barrier pair per K-tile.
// SWZ=1 (H GEMM, grid (16,64)): XCD k owns col-tiles [8k,8k+8) -> its 1MB
//   B-panel chunk is fetched into one L2 and reused by 16 row-blocks.
// SWZ=2 (node GEMMs, grid (640,1)): XCD-paired rows — both col-halves of a
//   row-panel land on the SAME XCD, ids 8 apart (near-concurrent), so each
//   128KB split-A panel is fetched into exactly one L2 instead of two.
//   Mapping: xcd=id&7, k=id>>3 in [0,80), by=k&1, bx=xcd*40+(k>>1);
//   bx>=313 -> idle (14 blocks). Bijective onto [0,313)x[0,2).
// Blocks with blockIdx.x >= mTiles run the fused dinv computation instead.
template <int BM, int BN, int SWZ>
__global__ __launch_bounds__(256) void gemm_mfma(
        const unsigned short* __restrict__ Ahi, const unsigned short* __restrict__ Alo,
        const unsigned short* __restrict__ BThi, const unsigned short* __restrict__ BTlo,
        float* __restrict__ C, unsigned short* __restrict__ Cbf,
        int M, int K, int N, int mTiles,
        const int* __restrict__ cur_d, const int* __restrict__ cur_p,
        float* __restrict__ dinv) {
    if ((int)blockIdx.x >= mTiles) {
        int i = (((int)blockIdx.x - mTiles) * (int)gridDim.y + (int)blockIdx.y) * 256
                + (int)threadIdx.x;
        if (i < N_NODES) {
            int deg = (i < NUM_DRUGS) ? cur_d[i * STRD] : cur_p[i * STRP];
            dinv[i] = rsqrtf((float)(deg + 1));
        }
        return;
    }
    constexpr int MI = BM / 32;           // acc row-frags per wave
    constexpr int NJ = BN / 32;           // acc col-frags per wave
    __shared__ unsigned short sAh[2][BM * 32], sAl[2][BM * 32];
    __shared__ unsigned short sBh[2][BN * 32], sBl[2][BN * 32];
    int t = threadIdx.x;
    int wv = t >> 6, lane = t & 63, quad = lane >> 4, l15 = lane & 15;
    int bx = blockIdx.x, by = blockIdx.y;
    if constexpr (SWZ == 1) {
        // H-GEMM grid (16,64): linear id -> XCD k owns col-tiles [8k,8k+8)
        int w = by * 16 + bx;
        int xcd = w & 7, j = w >> 3;
        bx = j & 15;
        by = xcd * 8 + (j >> 4);
    }
    if constexpr (SWZ == 2) {
        int id = bx;
        int xcd = id & 7, k = id >> 3;    // k in [0,80)
        by = k & 1;
        bx = xcd * 40 + (k >> 1);
        if (bx >= MT_NODE) return;        // 14 idle pad blocks
    }
    int m0 = bx * BM, n0 = by * BN;
    int m0w = (wv >> 1) * (BM / 2), n0w = (wv & 1) * (BN / 2);
    floatx4 zero = {0.f, 0.f, 0.f, 0.f};
    floatx4 acc[MI][NJ];
#pragma unroll
    for (int i = 0; i < MI; i++)
#pragma unroll
        for (int j = 0; j < NJ; j++) acc[i][j] = zero;

    auto STAGE = [&](int buf, int kk) {
#pragma unroll
        for (int s = t; s < BM * 4; s += 256) {   // A slots
            int row = s >> 2, pos = s & 3;
            int ch = pos ^ ((row >> 1) & 3);      // XOR-swizzled chunk
            int arow = m0 + row; if (arow > M - 1) arow = M - 1;
            size_t aoff = (size_t)arow * K + kk + ch * 8;
            gload16(Ahi + aoff, &sAh[buf][s * 8]);
            gload16(Alo + aoff, &sAl[buf][s * 8]);
        }
#pragma unroll
        for (int s = t; s < BN * 4; s += 256) {   // B slots
            int row = s >> 2, pos = s & 3;
            int ch = pos ^ ((row >> 1) & 3);
            int brow = n0 + row; if (brow > N - 1) brow = N - 1;
            size_t boff = (size_t)brow * K + kk + ch * 8;
            gload16(BThi + boff, &sBh[buf][s * 8]);
            gload16(BTlo + boff, &sBl[buf][s * 8]);
        }
    };

    int nk = K >> 5;
    STAGE(0, 0);
    asm volatile("s_waitcnt vmcnt(0)" ::: "memory");
    __builtin_amdgcn_s_barrier();
    int cur = 0;
    for (int it = 0; it < nk; ++it) {
        if (it + 1 < nk) STAGE(cur ^ 1, (it + 1) << 5);   // prefetch next tile
        short8 ah[MI], al[MI], bh[NJ], bl[NJ];
        int posq = quad ^ ((l15 >> 1) & 3);
#pragma unroll
        for (int i = 0; i < MI; i++) {
            int sl = (m0w + i * 16 + l15) * 4 + posq;
            ah[i] = *(const short8*)&sAh[cur][sl * 8];
            al[i] = *(const short8*)&sAl[cur][sl * 8];
        }
#pragma unroll
        for (int j = 0; j < NJ; j++) {
            int sl = (n0w + j * 16 + l15) * 4 + posq;
            bh[j] = *(const short8*)&sBh[cur][sl * 8];
            bl[j] = *(const short8*)&sBl[cur][sl * 8];
        }
#pragma unroll
        for (int i = 0; i < MI; i++)
#pragma unroll
            for (int j = 0; j < NJ; j++) {
                acc[i][j] = __builtin_amdgcn_mfma_f32_16x16x32_bf16(ah[i], bh[j], acc[i][j], 0, 0, 0);
                acc[i][j] = __builtin_amdgcn_mfma_f32_16x16x32_bf16(ah[i], bl[j], acc[i][j], 0, 0, 0);
                acc[i][j] = __builtin_amdgcn_mfma_f32_16x16x32_bf16(al[i], bh[j], acc[i][j], 0, 0, 0);
            }
        if (it + 1 < nk) {
            asm volatile("s_waitcnt vmcnt(0)" ::: "memory");  // next tile landed
            __builtin_amdgcn_s_barrier();                     // all reads of cur done
            cur ^= 1;
        }
    }
#pragma unroll
    for (int i = 0; i < MI; i++) {
        int gr = m0 + m0w + i * 16 + quad * 4;
#pragma unroll
        for (int r = 0; r < 4; r++) {
            if (gr + r < M) {
#pragma unroll
                for (int j = 0; j < NJ; j++) {
                    size_t o = (size_t)(gr + r) * N + n0 + n0w + j * 16 + l15;
                    float v = acc[i][j][r];
                    if (C) C[o] = v;
                    if (Cbf) Cbf[o] = f2bf(v);
                }
            }
        }
    }
}

// ---------------------------------------------------------------------------
// Layer-1 GCN aggregate — ALL reads bf16 (t1bf). Drug destinations: one BLOCK
// per drug (4 waves stride-4, LDS combine). Protein destinations: one wave
// each (deg ~11), 4/block.
__global__ __launch_bounds__(256) void aggregate1(const unsigned short* __restrict__ tmpbf,
                                                  const int* __restrict__ cur_d,
                                                  const int* __restrict__ adj_drug,
                                                  const int* __restrict__ cur_p,
                                                  const int* __restrict__ adj_prot,
                                                  const float* __restrict__ dinv,
                                                  const float* __restrict__ bias,
                                                  unsigned short* __restrict__ outhi,
                                                  unsigned short* __restrict__ outlo) {
    __shared__ float4 red[4][64];
    int b = blockIdx.x;
    int lane = threadIdx.x & 63;
    if (b < NB_AGG_D) {
        int d = b;
        int w = threadIdx.x >> 6;
        const int* adj = adj_drug + (size_t)d * ELLD;
        int ecnt = cur_d[d * STRD];
        int e = ecnt < ELLD ? ecnt : ELLD;
        float4 a0 = make_float4(0.f, 0.f, 0.f, 0.f);
        float4 a1 = a0, a2 = a0, a3 = a0;
        int idx = w;
        for (; idx + 12 < e; idx += 16) {
            int j0 = adj[idx], j1 = adj[idx + 4], j2 = adj[idx + 8], j3 = adj[idx + 12];
            float d0 = dinv[j0], d1 = dinv[j1], d2 = dinv[j2], d3 = dinv[j3];
            float4 v0 = bf4(&tmpbf[(size_t)j0 * CDIM + lane * 4]);
            float4 v1 = bf4(&tmpbf[(size_t)j1 * CDIM + lane * 4]);
            float4 v2 = bf4(&tmpbf[(size_t)j2 * CDIM + lane * 4]);
            float4 v3 = bf4(&tmpbf[(size_t)j3 * CDIM + lane * 4]);
            a0 = f4fma(v0, d0, a0);
            a1 = f4fma(v1, d1, a1);
            a2 = f4fma(v2, d2, a2);
            a3 = f4fma(v3, d3, a3);
        }
        for (; idx < e; idx += 4) {
            int j = adj[idx];
            a0 = f4fma(bf4(&tmpbf[(size_t)j * CDIM + lane * 4]), dinv[j], a0);
        }
        a0.x = (a0.x + a1.x) + (a2.x + a3.x);
        a0.y = (a0.y + a1.y) + (a2.y + a3.y);
        a0.z = (a0.z + a1.z) + (a2.z + a3.z);
        a0.w = (a0.w + a1.w) + (a2.w + a3.w);
        red[w][lane] = a0;
        __syncthreads();
        if (w == 0) {
            float di = dinv[d];
            float4 r0 = red[0][lane], r1 = red[1][lane], r2 = red[2][lane], r3 = red[3][lane];
            float4 self = bf4(&tmpbf[(size_t)d * CDIM + lane * 4]);
            float4 acc;
            acc.x = (r0.x + r1.x) + (r2.x + r3.x) + self.x * di;
            acc.y = (r0.y + r1.y) + (r2.y + r3.y) + self.y * di;
            acc.z = (r0.z + r1.z) + (r2.z + r3.z) + self.z * di;
            acc.w = (r0.w + r1.w) + (r2.w + r3.w) + self.w * di;
            float4 bv = ((const float4*)bias)[lane];
            float4 r;
            r.x = fmaxf(fmaf(acc.x, di, bv.x), 0.f);
            r.y = fmaxf(fmaf(acc.y, di, bv.y), 0.f);
            r.z = fmaxf(fmaf(acc.z, di, bv.z), 0.f);
            r.w = fmaxf(fmaf(acc.w, di, bv.w), 0.f);
            ushort4 h, l;
            split2(r.x, h.x, l.x); split2(r.y, h.y, l.y);
            split2(r.z, h.z, l.z); split2(r.w, h.w, l.w);
            *(ushort4*)&outhi[(size_t)d * CDIM + lane * 4] = h;
            *(ushort4*)&outlo[(size_t)d * CDIM + lane * 4] = l;
        }
        return;
    }
    // protein destinations: one wave per node, bf16 gathers
    int i = NUM_DRUGS + (b - NB_AGG_D) * 4 + (threadIdx.x >> 6);
    if (i >= N_NODES) return;
    float di = dinv[i];
    float4 a0 = make_float4(0.f, 0.f, 0.f, 0.f);
    float4 a1 = a0, a2 = a0, a3 = a0;
    const int* adj = adj_prot + (size_t)i * ELLP;
    int e = cur_p[i * STRP];
    int idx = 0;
    for (; idx + 4 <= e; idx += 4) {
        int j0 = adj[idx + 0], j1 = adj[idx + 1];
        int j2 = adj[idx + 2], j3 = adj[idx + 3];
        float d0 = dinv[j0], d1 = dinv[j1], d2 = dinv[j2], d3 = dinv[j3];
        float4 v0 = bf4(&tmpbf[(size_t)j0 * CDIM + lane * 4]);
        float4 v1 = bf4(&tmpbf[(size_t)j1 * CDIM + lane * 4]);
        float4 v2 = bf4(&tmpbf[(size_t)j2 * CDIM + lane * 4]);
        float4 v3 = bf4(&tmpbf[(size_t)j3 * CDIM + lane * 4]);
        a0 = f4fma(v0, d0, a0);
        a1 = f4fma(v1, d1, a1);
        a2 = f4fma(v2, d2, a2);
        a3 = f4fma(v3, d3, a3);
    }
    for (; idx < e; idx++) {
        int j = adj[idx];
        a0 = f4fma(bf4(&tmpbf[(size_t)j * CDIM + lane * 4]), dinv[j], a0);
    }
    float4 self = bf4(&tmpbf[(size_t)i * CDIM + lane * 4]);
    float4 acc;
    acc.x = (a0.x + a1.x) + (a2.x + a3.x) + self.x * di;
    acc.y = (a0.y + a1.y) + (a2.y + a3.y) + self.y * di;
    acc.z = (a0.z + a1.z) + (a2.z + a3.z) + self.z * di;
    acc.w = (a0.w + a1.w) + (a2.w + a3.w) + self.w * di;
    float4 bv = ((const float4*)bias)[lane];
    float4 r;
    r.x = fmaxf(fmaf(acc.x, di, bv.x), 0.f);
    r.y = fmaxf(fmaf(acc.y, di, bv.y), 0.f);
    r.z = fmaxf(fmaf(acc.z, di, bv.z), 0.f);
    r.w = fmaxf(fmaf(acc.w, di, bv.w), 0.f);
    ushort4 h, l;
    split2(r.x, h.x, l.x); split2(r.y, h.y, l.y);
    split2(r.z, h.z, l.z); split2(r.w, h.w, l.w);
    *(ushort4*)&outhi[(size_t)i * CDIM + lane * 4] = h;
    *(ushort4*)&outlo[(size_t)i * CDIM + lane * 4] = l;
}

// Layer-2 GCN aggregate, PROTEIN rows only, bf16 gathers (t2bf).
__global__ __launch_bounds__(256) void aggregate2p(const unsigned short* __restrict__ t2bf,
                                                   const int* __restrict__ cur_p,
                                                   const int* __restrict__ adj_prot,
                                                   const float* __restrict__ dinv,
                                                   const float* __restrict__ bias,
                                                   unsigned short* __restrict__ h2bf) {
    int w = (blockIdx.x * blockDim.x + threadIdx.x) >> 6;
    int lane = threadIdx.x & 63;
    if (w >= N_PROT) return;
    int i = NUM_DRUGS + w;
    float di = dinv[i];
    float4 a0 = make_float4(0.f, 0.f, 0.f, 0.f);
    float4 a1 = a0, a2 = a0, a3 = a0;
    const int* adj = adj_prot + (size_t)i * ELLP;
    int e = cur_p[i * STRP];
    int idx = 0;
    for (; idx + 4 <= e; idx += 4) {
        int j0 = adj[idx + 0], j1 = adj[idx + 1];
        int j2 = adj[idx + 2], j3 = adj[idx + 3];
        float d0 = dinv[j0], d1 = dinv[j1], d2 = dinv[j2], d3 = dinv[j3];
        float4 v0 = bf4(&t2bf[(size_t)j0 * CDIM + lane * 4]);
        float4 v1 = bf4(&t2bf[(size_t)j1 * CDIM + lane * 4]);
        float4 v2 = bf4(&t2bf[(size_t)j2 * CDIM + lane * 4]);
        float4 v3 = bf4(&t2bf[(size_t)j3 * CDIM + lane * 4]);
        a0 = f4fma(v0, d0, a0);
        a1 = f4fma(v1, d1, a1);
        a2 = f4fma(v2, d2, a2);
        a3 = f4fma(v3, d3, a3);
    }
    for (; idx < e; idx++) {
        int j = adj[idx];
        a0 = f4fma(bf4(&t2bf[(size_t)j * CDIM + lane * 4]), dinv[j], a0);
    }
    float4 self = bf4(&t2bf[(size_t)i * CDIM + lane * 4]);
    float4 acc;
    acc.x = (a0.x + a1.x) + (a2.x + a3.x) + self.x * di;
    acc.y = (a0.y + a1.y) + (a2.y + a3.y) + self.y * di;
    acc.z = (a0.z + a1.z) + (a2.z + a3.z) + self.z * di;
    acc.w = (a0.w + a1.w) + (a2.w + a3.w) + self.w * di;
    float4 bv = ((const float4*)bias)[lane];
    ushort4 o;
    o.x = f2bf(fmaxf(fmaf(acc.x, di, bv.x), 0.f));
    o.y = f2bf(fmaxf(fmaf(acc.y, di, bv.y), 0.f));
    o.z = f2bf(fmaxf(fmaf(acc.z, di, bv.z), 0.f));
    o.w = f2bf(fmaxf(fmaf(acc.w, di, bv.w), 0.f));
    *(ushort4*)&h2bf[(size_t)i * CDIM + lane * 4] = o;
}

// scatter-mean pool from bf16 h2 -> split-bf16 graph embeddings.
// One BLOCK per drug: 4 waves split the neighbor list (stride 4), LDS combine.
__global__ __launch_bounds__(256) void pool_drugs(const unsigned short* __restrict__ h2bf,
                                                  unsigned short* __restrict__ Ghi,
                                                  unsigned short* __restrict__ Glo,
                                                  const int* __restrict__ cur_d,
                                                  const int* __restrict__ adj_drug) {
    __shared__ float4 red[4][64];
    int d = blockIdx.x;
    int w = threadIdx.x >> 6, lane = threadIdx.x & 63;
    const int* adj = adj_drug + (size_t)d * ELLD;
    int ecnt = cur_d[d * STRD];
    int e = ecnt < ELLD ? ecnt : ELLD;
    float4 a0 = make_float4(0.f, 0.f, 0.f, 0.f);
    float4 a1 = a0, a2 = a0, a3 = a0;
    int idx = w;
    for (; idx + 12 < e; idx += 16) {
        int j0 = adj[idx], j1 = adj[idx + 4], j2 = adj[idx + 8], j3 = adj[idx + 12];
        float4 v0 = bf4(&h2bf[(size_t)j0 * CDIM + lane * 4]);
        float4 v1 = bf4(&h2bf[(size_t)j1 * CDIM + lane * 4]);
        float4 v2 = bf4(&h2bf[(size_t)j2 * CDIM + lane * 4]);
        float4 v3 = bf4(&h2bf[(size_t)j3 * CDIM + lane * 4]);
        a0.x += v0.x; a0.y += v0.y; a0.z += v0.z; a0.w += v0.w;
        a1.x += v1.x; a1.y += v1.y; a1.z += v1.z; a1.w += v1.w;
        a2.x += v2.x; a2.y += v2.y; a2.z += v2.z; a2.w += v2.w;
        a3.x += v3.x; a3.y += v3.y; a3.z += v3.z; a3.w += v3.w;
    }
    for (; idx < e; idx += 4) {
        float4 v = bf4(&h2bf[(size_t)adj[idx] * CDIM + lane * 4]);
        a0.x += v.x; a0.y += v.y; a0.z += v.z; a0.w += v.w;
    }
    a0.x = (a0.x + a1.x) + (a2.x + a3.x);
    a0.y = (a0.y + a1.y) + (a2.y + a3.y);
    a0.z = (a0.z + a1.z) + (a2.z + a3.z);
    a0.w = (a0.w + a1.w) + (a2.w + a3.w);
    red[w][lane] = a0;
    __syncthreads();
    if (w == 0) {
        float4 r0 = red[0][lane], r1 = red[1][lane], r2 = red[2][lane], r3 = red[3][lane];
        float4 acc;
        acc.x = (r0.x + r1.x) + (r2.x + r3.x);
        acc.y = (r0.y + r1.y) + (r2.y + r3.y);
        acc.z = (r0.z + r1.z) + (r2.z + r3.z);
        acc.w = (r0.w + r1.w) + (r2.w + r3.w);
        float sc = 1.f / (float)(ecnt > 1 ? ecnt : 1);
        acc.x *= sc; acc.y *= sc; acc.z *= sc; acc.w *= sc;
        ushort4 h, l;
        split2(acc.x, h.x, l.x); split2(acc.y, h.y, l.y);
        split2(acc.z, h.z, l.z); split2(acc.w, h.w, l.w);
        *(ushort4*)&Ghi[(size_t)d * CDIM + lane * 4] = h;
        *(ushort4*)&Glo[(size_t)d * CDIM + lane * 4] = l;
    }
}

// ---------------------------------------------------------------------------
// MLP epilogue: out[r] = sum_n relu(H[d0][2c*512+n] + H[d1][(2c+1)*512+n]
//                                   + b1[c][n]) * W2[c][n] + b2[c]
// H in bf16; one wave per row; lane covers 8 cols -> single pass, 16B loads.
__global__ __launch_bounds__(256) void mlp_out(const unsigned short* __restrict__ Hbf,
                                               const int* __restrict__ ddb,
                                               const int* __restrict__ ecl,
                                               const float* __restrict__ b1,
                                               const float* __restrict__ W2,
                                               const float* __restrict__ b2,
                                               float* __restrict__ outp) {
    int r = (blockIdx.x * blockDim.x + threadIdx.x) >> 6;
    int lane = threadIdx.x & 63;
    if (r >= BATCH) return;
    int c = ecl[r];
    int d0 = ddb[r], d1 = ddb[BATCH + r];
    int n = lane * 8;
    const unsigned short* h0 = Hbf + (size_t)d0 * HN + (size_t)(c * 2) * HID + n;
    const unsigned short* h1 = Hbf + (size_t)d1 * HN + (size_t)(c * 2 + 1) * HID + n;
    const float* b1e = b1 + (size_t)c * HID + n;
    const float* w2e = W2 + (size_t)c * HID + n;
    short8 a8 = *(const short8*)h0;
    short8 b8 = *(const short8*)h1;
    float4 bb0 = *(const float4*)(b1e);
    float4 bb1 = *(const float4*)(b1e + 4);
    float4 w0 = *(const float4*)(w2e);
    float4 w1 = *(const float4*)(w2e + 4);
    float s = 0.f;
    float h;
    h = bf2f((unsigned short)a8[0]) + bf2f((unsigned short)b8[0]) + bb0.x;
    s = fmaf(fmaxf(h, 0.f), w0.x, s);
    h = bf2f((unsigned short)a8[1]) + bf2f((unsigned short)b8[1]) + bb0.y;
    s = fmaf(fmaxf(h, 0.f), w0.y, s);
    h = bf2f((unsigned short)a8[2]) + bf2f((unsigned short)b8[2]) + bb0.z;
    s = fmaf(fmaxf(h, 0.f), w0.z, s);
    h = bf2f((unsigned short)a8[3]) + bf2f((unsigned short)b8[3]) + bb0.w;
    s = fmaf(fmaxf(h, 0.f), w0.w, s);
    h = bf2f((unsigned short)a8[4]) + bf2f((unsigned short)b8[4]) + bb1.x;
    s = fmaf(fmaxf(h, 0.f), w1.x, s);
    h = bf2f((unsigned short)a8[5]) + bf2f((unsigned short)b8[5]) + bb1.y;
    s = fmaf(fmaxf(h, 0.f), w1.y, s);
    h = bf2f((unsigned short)a8[6]) + bf2f((unsigned short)b8[6]) + bb1.z;
    s = fmaf(fmaxf(h, 0.f), w1.z, s);
    h = bf2f((unsigned short)a8[7]) + bf2f((unsigned short)b8[7]) + bb1.w;
    s = fmaf(fmaxf(h, 0.f), w1.w, s);
    s += __shfl_xor(s, 1);
    s += __shfl_xor(s, 2);
    s += __shfl_xor(s, 4);
    s += __shfl_xor(s, 8);
    s += __shfl_xor(s, 16);
    s += __shfl_xor(s, 32);
    if (lane == 0) outp[r] = s + b2[c];
}

// ---------------------------------------------------------------------------
extern "C" void kernel_launch(void* const* d_in, const int* in_sizes, int n_in,
                              void* d_out, int out_size, void* d_ws, size_t ws_size,
                              hipStream_t stream) {
    const float* x   = (const float*)d_in[0];
    const int* ei    = (const int*)d_in[1];
    const int* ddb   = (const int*)d_in[2];
    const int* ecl   = (const int*)d_in[3];
    const float* Wg1 = (const float*)d_in[5];
    const float* bg1 = (const float*)d_in[6];
    const float* Wg2 = (const float*)d_in[7];
    const float* bg2 = (const float*)d_in[8];
    const float* W1  = (const float*)d_in[9];
    const float* b1  = (const float*)d_in[10];
    const float* W2  = (const float*)d_in[11];
    const float* b2  = (const float*)d_in[12];
    float* outp = (float*)d_out;

    const size_t NC = (size_t)N_NODES * CDIM;                      // 5.12M elems
    const size_t HRES = (size_t)NUM_DRUGS * HN * sizeof(float);    // 67.1 MB reserved
    // Region 0 (inside reserved extent; all dead before the H GEMM writes Hbf):
    // Hbf (bf16, 33.6 MB) overlaps t2bf/t1bf/h1 — all dead at H-GEMM time.
    char* r0 = (char*)d_ws;
    unsigned short* Hbf   = (unsigned short*)d_ws;
    unsigned short* t2bf  = (unsigned short*)r0;                   // 10.24 MB
    unsigned short* t1bf  = (unsigned short*)(r0 + 20480000);
    unsigned short* h2bf  = t1bf;
    unsigned short* h1hi  = (unsigned short*)(r0 + 30720000);
    unsigned short* h1lo  = (unsigned short*)(r0 + 40960000);
    unsigned short* xhi   = h1hi;
    unsigned short* xlo   = h1lo;
    char* p = r0 + 51200000;
    auto alloc = [&](size_t bytes) {
        char* r = p;
        p += (bytes + 255) & ~size_t(255);
        return (void*)r;
    };
    float* dinv    = (float*)alloc(sizeof(float) * N_NODES);
    int* cur_d     = (int*)alloc(sizeof(int) * NUM_DRUGS * STRD);
    int* cur_p     = (int*)alloc(sizeof(int) * N_NODES * STRP);
    int* adj_drug  = (int*)alloc(sizeof(int) * NUM_DRUGS * ELLD);
    int* adj_prot  = (int*)alloc(sizeof(int) * (size_t)N_NODES * ELLP);
    // Region 1 (after reserved extent): buffers the H GEMM reads
    p = (char*)d_ws + ((HRES + 255) & ~size_t(255));
    unsigned short* Ghi   = (unsigned short*)alloc(2 * NUM_DRUGS * CDIM);
    unsigned short* Glo   = (unsigned short*)alloc(2 * NUM_DRUGS * CDIM);
    unsigned short* wg1Th = (unsigned short*)alloc(2 * CDIM * CDIM);
    unsigned short* wg1Tl = (unsigned short*)alloc(2 * CDIM * CDIM);
    unsigned short* wg2Th = (unsigned short*)alloc(2 * CDIM * CDIM);
    unsigned short* wg2Tl = (unsigned short*)alloc(2 * CDIM * CDIM);
    unsigned short* W1Th  = (unsigned short*)alloc(2 * (size_t)N_CL * HID * HID);
    unsigned short* W1Tl  = (unsigned short*)alloc(2 * (size_t)N_CL * HID * HID);

    // zero counters (tiny kernel; fill range in prep_all depends on it in
    // stream order)
    zero_counts<<<(N_NODES + 255) / 256, 256, 0, stream>>>(cur_d, cur_p);
    // fused prep: ELL fill + x split + Wg transposes + W1 transpose (1 dispatch;
    // fill's atomic latency hides under the bandwidth-bound ranges)
    prep_all<<<NB_FILL + NB_T64 + NB_TWG + NB_SPLIT, 256, 0, stream>>>(
        ei, cur_d, adj_drug, cur_p, adj_prot,
        x, xhi, xlo, Wg1, Wg2, wg1Th, wg1Tl, wg2Th, wg2Tl, W1, W1Th, W1Tl);
    // GCN layer 1: bf16-only output (t1bf); XCD-paired rows (SWZ=2);
    // dinv fused as 79 extra blocks (blockIdx.x >= 640).
    gemm_mfma<64, 128, 2><<<dim3(NB_GNODE + 79, 1), 256, 0, stream>>>(
        xhi, xlo, wg1Th, wg1Tl, nullptr, t1bf, N_NODES, CDIM, CDIM,
        NB_GNODE, cur_d, cur_p, dinv);
    aggregate1<<<NB_AGG_D + NB_AGG_P, 256, 0, stream>>>(
        t1bf, cur_d, adj_drug, cur_p, adj_prot, dinv, bg1, h1hi, h1lo);
    // GCN layer 2: bf16-only output (t2bf); XCD-paired rows.
    gemm_mfma<64, 128, 2><<<dim3(NB_GNODE, 1), 256, 0, stream>>>(
        h1hi, h1lo, wg2Th, wg2Tl, nullptr, t2bf, N_NODES, CDIM, CDIM,
        NB_GNODE, nullptr, nullptr, nullptr);
    aggregate2p<<<(N_PROT * 64 + 255) / 256, 256, 0, stream>>>(
        t2bf, cur_p, adj_prot, dinv, bg2, h2bf);
    // pool (bf16 gather, 4 waves/drug) -> split graph embeddings
    pool_drugs<<<NUM_DRUGS, 256, 0, stream>>>(h2bf, Ghi, Glo, cur_d, adj_drug);
    // MLP precompute: Hbf[2048, 8192] (bf16) = G @ W1cat
    // 128x128 2-phase dbuf (best-measured config), XCD-swizzled (16,64) grid
    gemm_mfma<128, 128, 1><<<dim3(NUM_DRUGS / 128, HN / 128), 256, 0, stream>>>(
        Ghi, Glo, W1Th, W1Tl, nullptr, Hbf, NUM_DRUGS, CDIM, HN,
        NUM_DRUGS / 128, nullptr, nullptr, nullptr);
    // epilogue: gather 2 Hbf rows per batch row, relu+dot, direct store
    mlp_out<<<(BATCH * 64) / 256, 256, 0, stream>>>(Hbf, ddb, ecl, b1, W2, b2, outp);
}

// Round 11
// 233.193 us; speedup vs baseline: 1.0711x; 1.0711x over previous
//
#include <hip/hip_runtime.h>
#include <hip/hip_bf16.h>

// Problem constants (fixed by reference)
#define N_NODES 20000
#define NUM_DRUGS 2048
#define N_PROT (N_NODES - NUM_DRUGS)
#define NUM_DPI 200000
#define E2 400000          // 2*NUM_DPI directed edges
#define CDIM 256           // IN_C == EMB == 256
#define HID 512
#define N_CL 8
#define BATCH 16384
#define HN 8192            // H cols = 8 experts x 2 halves x 512

#define STRD 32            // drug counter padding (ints) = 1 line per counter
#define STRP 16            // protein counter padding
#define ELLD 192           // drug ELL stride (mean deg 97.7, +9.5 sigma)
#define ELLP 48            // protein ELL stride (mean deg 11.1, +11 sigma)

// fused-prep block ranges
#define NB_FILL 782        // ELL fill: 200000 / 256
#define NB_T64 512         // W1 transpose: 4 x 8 x 16
#define NB_TWG 32          // Wg1/Wg2 transpose: 4 x 4 x 2
#define NB_SPLIT 20000     // x split: 5.12M / 256

// node-GEMM tiling (BM=64): 313 row tiles; XCD-paired grid of 640 (8 x 80)
#define MT_NODE 313
#define NB_GNODE 640       // 8 XCDs x 80 slots (40 row-panels x 2 col-halves; 14 idle)

// aggregate1 grid split
#define NB_AGG_D NUM_DRUGS              // 1 block per drug (4 waves)
#define NB_AGG_P ((N_PROT + 3) / 4)     // 4 proteins per block (1 wave each)

typedef __attribute__((ext_vector_type(8))) short short8;   // 8 bf16 (MFMA A/B frag)
typedef __attribute__((ext_vector_type(4))) float floatx4;  // MFMA C/D frag

__device__ inline unsigned short f2bf(float f) {
    unsigned u = __float_as_uint(f);
    u += 0x7fff + ((u >> 16) & 1);   // RNE
    return (unsigned short)(u >> 16);
}
__device__ inline float bf2f(unsigned short h) {
    return __uint_as_float((unsigned)h << 16);
}
__device__ inline void split2(float v, unsigned short& h, unsigned short& l) {
    h = f2bf(v);
    l = f2bf(v - bf2f(h));
}
__device__ inline void gload16(const void* g, void* l) {
    __builtin_amdgcn_global_load_lds(
        (const __attribute__((address_space(1))) void*)g,
        (__attribute__((address_space(3))) void*)l, 16, 0, 0);
}
__device__ inline float4 f4fma(float4 v, float s, float4 a) {
    a.x = fmaf(v.x, s, a.x); a.y = fmaf(v.y, s, a.y);
    a.z = fmaf(v.z, s, a.z); a.w = fmaf(v.w, s, a.w);
    return a;
}
__device__ inline float4 bf4(const unsigned short* p) {
    ushort4 q = *(const ushort4*)p;
    return make_float4(bf2f(q.x), bf2f(q.y), bf2f(q.z), bf2f(q.w));
}

// ---------------------------------------------------------------------------
// counter zeroing (tiny dispatch)
__global__ void zero_counts(int* cur_d, int* cur_p) {
    int i = blockIdx.x * blockDim.x + threadIdx.x;
    if (i < N_NODES) cur_p[i * STRP] = 0;
    if (i < NUM_DRUGS) cur_d[i * STRD] = 0;
}

// ---------------------------------------------------------------------------
// Fused prep: ELL fill | W1 transpose-split | Wg1/Wg2 transpose-split |
// x split. Counters zeroed by the preceding zero_counts dispatch.
__global__ __launch_bounds__(256) void prep_all(
        const int* __restrict__ ei, int* __restrict__ cur_d,
        int* __restrict__ adj_drug, int* __restrict__ cur_p,
        int* __restrict__ adj_prot,
        const float* __restrict__ x, unsigned short* __restrict__ xhi,
        unsigned short* __restrict__ xlo,
        const float* __restrict__ Wg1, const float* __restrict__ Wg2,
        unsigned short* __restrict__ wg1Th, unsigned short* __restrict__ wg1Tl,
        unsigned short* __restrict__ wg2Th, unsigned short* __restrict__ wg2Tl,
        const float* __restrict__ W1, unsigned short* __restrict__ W1Th,
        unsigned short* __restrict__ W1Tl) {
    __shared__ float ld[64 * 65];
    int b = blockIdx.x;
    int t = threadIdx.x;
    int tx = t & 63, ty = t >> 6;
    if (b < NB_FILL) {
        int e = b * 256 + t;
        if (e < NUM_DPI) {
            int d = ei[e];
            int p = ei[E2 + e];
            int posd = atomicAdd(&cur_d[d * STRD], 1);
            int posp = atomicAdd(&cur_p[p * STRP], 1);
            if (posd < ELLD) adj_drug[d * ELLD + posd] = p;   // clamp
            if (posp < ELLP) adj_prot[(size_t)p * ELLP + posp] = d;
        }
        return;
    }
    b -= NB_FILL;
    if (b < NB_T64) {
        // W1 [16 slabs][256][512] -> W1cat^T [8192][256] split bf16
        int m = b >> 5;
        int k0 = (b & 3) * 64, n0 = ((b >> 2) & 7) * 64;
        const float* Wm = W1 + (size_t)m * CDIM * HID;
#pragma unroll
        for (int rr = 0; rr < 16; rr++) {
            int kl = rr * 4 + ty;
            ld[tx * 65 + kl] = Wm[(size_t)(k0 + kl) * HID + n0 + tx];
        }
        __syncthreads();
        size_t obase = (size_t)m * HID * CDIM;
#pragma unroll
        for (int rr = 0; rr < 16; rr++) {
            int nl = rr * 4 + ty;
            float v = ld[nl * 65 + tx];
            unsigned short h, l;
            split2(v, h, l);
            size_t o = obase + (size_t)(n0 + nl) * CDIM + k0 + tx;
            W1Th[o] = h;
            W1Tl[o] = l;
        }
        return;
    }
    b -= NB_T64;
    if (b < NB_TWG) {
        // Wg1/Wg2 [256][256] -> transposed split bf16
        const float* W = (b >> 4) ? Wg2 : Wg1;
        unsigned short* hi = (b >> 4) ? wg2Th : wg1Th;
        unsigned short* lo = (b >> 4) ? wg2Tl : wg1Tl;
        int k0 = (b & 3) * 64, n0 = ((b >> 2) & 3) * 64;
#pragma unroll
        for (int rr = 0; rr < 16; rr++) {
            int kl = rr * 4 + ty;
            ld[tx * 65 + kl] = W[(size_t)(k0 + kl) * CDIM + n0 + tx];
        }
        __syncthreads();
#pragma unroll
        for (int rr = 0; rr < 16; rr++) {
            int nl = rr * 4 + ty;
            float v = ld[nl * 65 + tx];
            unsigned short h, l;
            split2(v, h, l);
            size_t o = (size_t)(n0 + nl) * CDIM + k0 + tx;
            hi[o] = h;
            lo[o] = l;
        }
        return;
    }
    b -= NB_TWG;
    {   // x split: exactly NB_SPLIT blocks cover 5.12M elems
        int i = b * 256 + t;
        unsigned short h, l;
        split2(x[i], h, l);
        xhi[i] = h;
        xlo[i] = l;
    }
}

// ---------------------------------------------------------------------------
// split/single-bf16 MFMA GEMM: C[M,N] = A[M,K] @ B[K,N], B passed as B^T.
// ASPLIT=1: A is split (hi+lo), 3 MFMA/tile-pair. ASPLIT=0: A single bf16,
//   2 MFMA (A·Bhi + A·Blo) — halves A staging and cuts LDS:
//   gemm2 <64,128,0>: 40KB dbuf -> 4 blocks/CU; H GEMM <128,128,0>: 48KB
//   dbuf -> 3 blocks/CU (the high-intensity + higher-TLP quadrant).
// SWZ=1 (H GEMM): XCD k owns col-tiles [8k,8k+8).
// SWZ=2 (node GEMMs, grid (640,1)): XCD-paired rows, bijective onto
//   [0,313)x[0,2) with 14 idle blocks.
// Blocks with blockIdx.x >= mTiles run the fused dinv computation instead.
template <int BM, int BN, int SWZ, int ASPLIT>
__global__ __launch_bounds__(256) void gemm_mfma(
        const unsigned short* __restrict__ Ahi, const unsigned short* __restrict__ Alo,
        const unsigned short* __restrict__ BThi, const unsigned short* __restrict__ BTlo,
        float* __restrict__ C, unsigned short* __restrict__ Cbf,
        int M, int K, int N, int mTiles,
        const int* __restrict__ cur_d, const int* __restrict__ cur_p,
        float* __restrict__ dinv) {
    if ((int)blockIdx.x >= mTiles) {
        int i = (((int)blockIdx.x - mTiles) * (int)gridDim.y + (int)blockIdx.y) * 256
                + (int)threadIdx.x;
        if (i < N_NODES) {
            int deg = (i < NUM_DRUGS) ? cur_d[i * STRD] : cur_p[i * STRP];
            dinv[i] = rsqrtf((float)(deg + 1));
        }
        return;
    }
    constexpr int MI = BM / 32;           // acc row-frags per wave
    constexpr int NJ = BN / 32;           // acc col-frags per wave
    constexpr int ASZ = ASPLIT ? BM * 32 : 8;
    __shared__ unsigned short sAh[2][BM * 32], sAl[2][ASZ];
    __shared__ unsigned short sBh[2][BN * 32], sBl[2][BN * 32];
    int t = threadIdx.x;
    int wv = t >> 6, lane = t & 63, quad = lane >> 4, l15 = lane & 15;
    int bx = blockIdx.x, by = blockIdx.y;
    if constexpr (SWZ == 1) {
        // H-GEMM grid (16,64): linear id -> XCD k owns col-tiles [8k,8k+8)
        int w = by * 16 + bx;
        int xcd = w & 7, j = w >> 3;
        bx = j & 15;
        by = xcd * 8 + (j >> 4);
    }
    if constexpr (SWZ == 2) {
        int id = bx;
        int xcd = id & 7, k = id >> 3;    // k in [0,80)
        by = k & 1;
        bx = xcd * 40 + (k >> 1);
        if (bx >= MT_NODE) return;        // 14 idle pad blocks
    }
    int m0 = bx * BM, n0 = by * BN;
    int m0w = (wv >> 1) * (BM / 2), n0w = (wv & 1) * (BN / 2);
    floatx4 zero = {0.f, 0.f, 0.f, 0.f};
    floatx4 acc[MI][NJ];
#pragma unroll
    for (int i = 0; i < MI; i++)
#pragma unroll
        for (int j = 0; j < NJ; j++) acc[i][j] = zero;

    auto STAGE = [&](int buf, int kk) {
#pragma unroll
        for (int s = t; s < BM * 4; s += 256) {   // A slots
            int row = s >> 2, pos = s & 3;
            int ch = pos ^ ((row >> 1) & 3);      // XOR-swizzled chunk
            int arow = m0 + row; if (arow > M - 1) arow = M - 1;
            size_t aoff = (size_t)arow * K + kk + ch * 8;
            gload16(Ahi + aoff, &sAh[buf][s * 8]);
            if constexpr (ASPLIT) gload16(Alo + aoff, &sAl[buf][s * 8]);
        }
#pragma unroll
        for (int s = t; s < BN * 4; s += 256) {   // B slots
            int row = s >> 2, pos = s & 3;
            int ch = pos ^ ((row >> 1) & 3);
            int brow = n0 + row; if (brow > N - 1) brow = N - 1;
            size_t boff = (size_t)brow * K + kk + ch * 8;
            gload16(BThi + boff, &sBh[buf][s * 8]);
            gload16(BTlo + boff, &sBl[buf][s * 8]);
        }
    };

    int nk = K >> 5;
    STAGE(0, 0);
    asm volatile("s_waitcnt vmcnt(0)" ::: "memory");
    __builtin_amdgcn_s_barrier();
    int cur = 0;
    for (int it = 0; it < nk; ++it) {
        if (it + 1 < nk) STAGE(cur ^ 1, (it + 1) << 5);   // prefetch next tile
        short8 ah[MI], al[MI], bh[NJ], bl[NJ];
        int posq = quad ^ ((l15 >> 1) & 3);
#pragma unroll
        for (int i = 0; i < MI; i++) {
            int sl = (m0w + i * 16 + l15) * 4 + posq;
            ah[i] = *(const short8*)&sAh[cur][sl * 8];
            if constexpr (ASPLIT) al[i] = *(const short8*)&sAl[cur][sl * 8];
        }
#pragma unroll
        for (int j = 0; j < NJ; j++) {
            int sl = (n0w + j * 16 + l15) * 4 + posq;
            bh[j] = *(const short8*)&sBh[cur][sl * 8];
            bl[j] = *(const short8*)&sBl[cur][sl * 8];
        }
#pragma unroll
        for (int i = 0; i < MI; i++)
#pragma unroll
            for (int j = 0; j < NJ; j++) {
                acc[i][j] = __builtin_amdgcn_mfma_f32_16x16x32_bf16(ah[i], bh[j], acc[i][j], 0, 0, 0);
                acc[i][j] = __builtin_amdgcn_mfma_f32_16x16x32_bf16(ah[i], bl[j], acc[i][j], 0, 0, 0);
                if constexpr (ASPLIT)
                    acc[i][j] = __builtin_amdgcn_mfma_f32_16x16x32_bf16(al[i], bh[j], acc[i][j], 0, 0, 0);
            }
        if (it + 1 < nk) {
            asm volatile("s_waitcnt vmcnt(0)" ::: "memory");  // next tile landed
            __builtin_amdgcn_s_barrier();                     // all reads of cur done
            cur ^= 1;
        }
    }
#pragma unroll
    for (int i = 0; i < MI; i++) {
        int gr = m0 + m0w + i * 16 + quad * 4;
#pragma unroll
        for (int r = 0; r < 4; r++) {
            if (gr + r < M) {
#pragma unroll
                for (int j = 0; j < NJ; j++) {
                    size_t o = (size_t)(gr + r) * N + n0 + n0w + j * 16 + l15;
                    float v = acc[i][j][r];
                    if (C) C[o] = v;
                    if (Cbf) Cbf[o] = f2bf(v);
                }
            }
        }
    }
}

// ---------------------------------------------------------------------------
// Layer-1 GCN aggregate — reads bf16 (t1bf), writes h1 SINGLE bf16 (the
// gemm2 A-side is bf16 now; error channel measured-safe vs 8.8e-4 budget).
__global__ __launch_bounds__(256) void aggregate1(const unsigned short* __restrict__ tmpbf,
                                                  const int* __restrict__ cur_d,
                                                  const int* __restrict__ adj_drug,
                                                  const int* __restrict__ cur_p,
                                                  const int* __restrict__ adj_prot,
                                                  const float* __restrict__ dinv,
                                                  const float* __restrict__ bias,
                                                  unsigned short* __restrict__ outbf) {
    __shared__ float4 red[4][64];
    int b = blockIdx.x;
    int lane = threadIdx.x & 63;
    if (b < NB_AGG_D) {
        int d = b;
        int w = threadIdx.x >> 6;
        const int* adj = adj_drug + (size_t)d * ELLD;
        int ecnt = cur_d[d * STRD];
        int e = ecnt < ELLD ? ecnt : ELLD;
        float4 a0 = make_float4(0.f, 0.f, 0.f, 0.f);
        float4 a1 = a0, a2 = a0, a3 = a0;
        int idx = w;
        for (; idx + 12 < e; idx += 16) {
            int j0 = adj[idx], j1 = adj[idx + 4], j2 = adj[idx + 8], j3 = adj[idx + 12];
            float d0 = dinv[j0], d1 = dinv[j1], d2 = dinv[j2], d3 = dinv[j3];
            float4 v0 = bf4(&tmpbf[(size_t)j0 * CDIM + lane * 4]);
            float4 v1 = bf4(&tmpbf[(size_t)j1 * CDIM + lane * 4]);
            float4 v2 = bf4(&tmpbf[(size_t)j2 * CDIM + lane * 4]);
            float4 v3 = bf4(&tmpbf[(size_t)j3 * CDIM + lane * 4]);
            a0 = f4fma(v0, d0, a0);
            a1 = f4fma(v1, d1, a1);
            a2 = f4fma(v2, d2, a2);
            a3 = f4fma(v3, d3, a3);
        }
        for (; idx < e; idx += 4) {
            int j = adj[idx];
            a0 = f4fma(bf4(&tmpbf[(size_t)j * CDIM + lane * 4]), dinv[j], a0);
        }
        a0.x = (a0.x + a1.x) + (a2.x + a3.x);
        a0.y = (a0.y + a1.y) + (a2.y + a3.y);
        a0.z = (a0.z + a1.z) + (a2.z + a3.z);
        a0.w = (a0.w + a1.w) + (a2.w + a3.w);
        red[w][lane] = a0;
        __syncthreads();
        if (w == 0) {
            float di = dinv[d];
            float4 r0 = red[0][lane], r1 = red[1][lane], r2 = red[2][lane], r3 = red[3][lane];
            float4 self = bf4(&tmpbf[(size_t)d * CDIM + lane * 4]);
            float4 acc;
            acc.x = (r0.x + r1.x) + (r2.x + r3.x) + self.x * di;
            acc.y = (r0.y + r1.y) + (r2.y + r3.y) + self.y * di;
            acc.z = (r0.z + r1.z) + (r2.z + r3.z) + self.z * di;
            acc.w = (r0.w + r1.w) + (r2.w + r3.w) + self.w * di;
            float4 bv = ((const float4*)bias)[lane];
            ushort4 o;
            o.x = f2bf(fmaxf(fmaf(acc.x, di, bv.x), 0.f));
            o.y = f2bf(fmaxf(fmaf(acc.y, di, bv.y), 0.f));
            o.z = f2bf(fmaxf(fmaf(acc.z, di, bv.z), 0.f));
            o.w = f2bf(fmaxf(fmaf(acc.w, di, bv.w), 0.f));
            *(ushort4*)&outbf[(size_t)d * CDIM + lane * 4] = o;
        }
        return;
    }
    // protein destinations: one wave per node, bf16 gathers
    int i = NUM_DRUGS + (b - NB_AGG_D) * 4 + (threadIdx.x >> 6);
    if (i >= N_NODES) return;
    float di = dinv[i];
    float4 a0 = make_float4(0.f, 0.f, 0.f, 0.f);
    float4 a1 = a0, a2 = a0, a3 = a0;
    const int* adj = adj_prot + (size_t)i * ELLP;
    int e = cur_p[i * STRP];
    int idx = 0;
    for (; idx + 4 <= e; idx += 4) {
        int j0 = adj[idx + 0], j1 = adj[idx + 1];
        int j2 = adj[idx + 2], j3 = adj[idx + 3];
        float d0 = dinv[j0], d1 = dinv[j1], d2 = dinv[j2], d3 = dinv[j3];
        float4 v0 = bf4(&tmpbf[(size_t)j0 * CDIM + lane * 4]);
        float4 v1 = bf4(&tmpbf[(size_t)j1 * CDIM + lane * 4]);
        float4 v2 = bf4(&tmpbf[(size_t)j2 * CDIM + lane * 4]);
        float4 v3 = bf4(&tmpbf[(size_t)j3 * CDIM + lane * 4]);
        a0 = f4fma(v0, d0, a0);
        a1 = f4fma(v1, d1, a1);
        a2 = f4fma(v2, d2, a2);
        a3 = f4fma(v3, d3, a3);
    }
    for (; idx < e; idx++) {
        int j = adj[idx];
        a0 = f4fma(bf4(&tmpbf[(size_t)j * CDIM + lane * 4]), dinv[j], a0);
    }
    float4 self = bf4(&tmpbf[(size_t)i * CDIM + lane * 4]);
    float4 acc;
    acc.x = (a0.x + a1.x) + (a2.x + a3.x) + self.x * di;
    acc.y = (a0.y + a1.y) + (a2.y + a3.y) + self.y * di;
    acc.z = (a0.z + a1.z) + (a2.z + a3.z) + self.z * di;
    acc.w = (a0.w + a1.w) + (a2.w + a3.w) + self.w * di;
    float4 bv = ((const float4*)bias)[lane];
    ushort4 o;
    o.x = f2bf(fmaxf(fmaf(acc.x, di, bv.x), 0.f));
    o.y = f2bf(fmaxf(fmaf(acc.y, di, bv.y), 0.f));
    o.z = f2bf(fmaxf(fmaf(acc.z, di, bv.z), 0.f));
    o.w = f2bf(fmaxf(fmaf(acc.w, di, bv.w), 0.f));
    *(ushort4*)&outbf[(size_t)i * CDIM + lane * 4] = o;
}

// Layer-2 GCN aggregate, PROTEIN rows only, bf16 gathers (t2bf).
__global__ __launch_bounds__(256) void aggregate2p(const unsigned short* __restrict__ t2bf,
                                                   const int* __restrict__ cur_p,
                                                   const int* __restrict__ adj_prot,
                                                   const float* __restrict__ dinv,
                                                   const float* __restrict__ bias,
                                                   unsigned short* __restrict__ h2bf) {
    int w = (blockIdx.x * blockDim.x + threadIdx.x) >> 6;
    int lane = threadIdx.x & 63;
    if (w >= N_PROT) return;
    int i = NUM_DRUGS + w;
    float di = dinv[i];
    float4 a0 = make_float4(0.f, 0.f, 0.f, 0.f);
    float4 a1 = a0, a2 = a0, a3 = a0;
    const int* adj = adj_prot + (size_t)i * ELLP;
    int e = cur_p[i * STRP];
    int idx = 0;
    for (; idx + 4 <= e; idx += 4) {
        int j0 = adj[idx + 0], j1 = adj[idx + 1];
        int j2 = adj[idx + 2], j3 = adj[idx + 3];
        float d0 = dinv[j0], d1 = dinv[j1], d2 = dinv[j2], d3 = dinv[j3];
        float4 v0 = bf4(&t2bf[(size_t)j0 * CDIM + lane * 4]);
        float4 v1 = bf4(&t2bf[(size_t)j1 * CDIM + lane * 4]);
        float4 v2 = bf4(&t2bf[(size_t)j2 * CDIM + lane * 4]);
        float4 v3 = bf4(&t2bf[(size_t)j3 * CDIM + lane * 4]);
        a0 = f4fma(v0, d0, a0);
        a1 = f4fma(v1, d1, a1);
        a2 = f4fma(v2, d2, a2);
        a3 = f4fma(v3, d3, a3);
    }
    for (; idx < e; idx++) {
        int j = adj[idx];
        a0 = f4fma(bf4(&t2bf[(size_t)j * CDIM + lane * 4]), dinv[j], a0);
    }
    float4 self = bf4(&t2bf[(size_t)i * CDIM + lane * 4]);
    float4 acc;
    acc.x = (a0.x + a1.x) + (a2.x + a3.x) + self.x * di;
    acc.y = (a0.y + a1.y) + (a2.y + a3.y) + self.y * di;
    acc.z = (a0.z + a1.z) + (a2.z + a3.z) + self.z * di;
    acc.w = (a0.w + a1.w) + (a2.w + a3.w) + self.w * di;
    float4 bv = ((const float4*)bias)[lane];
    ushort4 o;
    o.x = f2bf(fmaxf(fmaf(acc.x, di, bv.x), 0.f));
    o.y = f2bf(fmaxf(fmaf(acc.y, di, bv.y), 0.f));
    o.z = f2bf(fmaxf(fmaf(acc.z, di, bv.z), 0.f));
    o.w = f2bf(fmaxf(fmaf(acc.w, di, bv.w), 0.f));
    *(ushort4*)&h2bf[(size_t)i * CDIM + lane * 4] = o;
}

// scatter-mean pool from bf16 h2 -> SINGLE bf16 graph embeddings (H GEMM
// A-side is bf16 now). One BLOCK per drug: 4 waves stride-4, LDS combine.
__global__ __launch_bounds__(256) void pool_drugs(const unsigned short* __restrict__ h2bf,
                                                  unsigned short* __restrict__ Gb,
                                                  const int* __restrict__ cur_d,
                                                  const int* __restrict__ adj_drug) {
    __shared__ float4 red[4][64];
    int d = blockIdx.x;
    int w = threadIdx.x >> 6, lane = threadIdx.x & 63;
    const int* adj = adj_drug + (size_t)d * ELLD;
    int ecnt = cur_d[d * STRD];
    int e = ecnt < ELLD ? ecnt : ELLD;
    float4 a0 = make_float4(0.f, 0.f, 0.f, 0.f);
    float4 a1 = a0, a2 = a0, a3 = a0;
    int idx = w;
    for (; idx + 12 < e; idx += 16) {
        int j0 = adj[idx], j1 = adj[idx + 4], j2 = adj[idx + 8], j3 = adj[idx + 12];
        float4 v0 = bf4(&h2bf[(size_t)j0 * CDIM + lane * 4]);
        float4 v1 = bf4(&h2bf[(size_t)j1 * CDIM + lane * 4]);
        float4 v2 = bf4(&h2bf[(size_t)j2 * CDIM + lane * 4]);
        float4 v3 = bf4(&h2bf[(size_t)j3 * CDIM + lane * 4]);
        a0.x += v0.x; a0.y += v0.y; a0.z += v0.z; a0.w += v0.w;
        a1.x += v1.x; a1.y += v1.y; a1.z += v1.z; a1.w += v1.w;
        a2.x += v2.x; a2.y += v2.y; a2.z += v2.z; a2.w += v2.w;
        a3.x += v3.x; a3.y += v3.y; a3.z += v3.z; a3.w += v3.w;
    }
    for (; idx < e; idx += 4) {
        float4 v = bf4(&h2bf[(size_t)adj[idx] * CDIM + lane * 4]);
        a0.x += v.x; a0.y += v.y; a0.z += v.z; a0.w += v.w;
    }
    a0.x = (a0.x + a1.x) + (a2.x + a3.x);
    a0.y = (a0.y + a1.y) + (a2.y + a3.y);
    a0.z = (a0.z + a1.z) + (a2.z + a3.z);
    a0.w = (a0.w + a1.w) + (a2.w + a3.w);
    red[w][lane] = a0;
    __syncthreads();
    if (w == 0) {
        float4 r0 = red[0][lane], r1 = red[1][lane], r2 = red[2][lane], r3 = red[3][lane];
        float4 acc;
        acc.x = (r0.x + r1.x) + (r2.x + r3.x);
        acc.y = (r0.y + r1.y) + (r2.y + r3.y);
        acc.z = (r0.z + r1.z) + (r2.z + r3.z);
        acc.w = (r0.w + r1.w) + (r2.w + r3.w);
        float sc = 1.f / (float)(ecnt > 1 ? ecnt : 1);
        ushort4 o;
        o.x = f2bf(acc.x * sc);
        o.y = f2bf(acc.y * sc);
        o.z = f2bf(acc.z * sc);
        o.w = f2bf(acc.w * sc);
        *(ushort4*)&Gb[(size_t)d * CDIM + lane * 4] = o;
    }
}

// ---------------------------------------------------------------------------
// MLP epilogue: out[r] = sum_n relu(H[d0][2c*512+n] + H[d1][(2c+1)*512+n]
//                                   + b1[c][n]) * W2[c][n] + b2[c]
__global__ __launch_bounds__(256) void mlp_out(const unsigned short* __restrict__ Hbf,
                                               const int* __restrict__ ddb,
                                               const int* __restrict__ ecl,
                                               const float* __restrict__ b1,
                                               const float* __restrict__ W2,
                                               const float* __restrict__ b2,
                                               float* __restrict__ outp) {
    int r = (blockIdx.x * blockDim.x + threadIdx.x) >> 6;
    int lane = threadIdx.x & 63;
    if (r >= BATCH) return;
    int c = ecl[r];
    int d0 = ddb[r], d1 = ddb[BATCH + r];
    int n = lane * 8;
    const unsigned short* h0 = Hbf + (size_t)d0 * HN + (size_t)(c * 2) * HID + n;
    const unsigned short* h1 = Hbf + (size_t)d1 * HN + (size_t)(c * 2 + 1) * HID + n;
    const float* b1e = b1 + (size_t)c * HID + n;
    const float* w2e = W2 + (size_t)c * HID + n;
    short8 a8 = *(const short8*)h0;
    short8 b8 = *(const short8*)h1;
    float4 bb0 = *(const float4*)(b1e);
    float4 bb1 = *(const float4*)(b1e + 4);
    float4 w0 = *(const float4*)(w2e);
    float4 w1 = *(const float4*)(w2e + 4);
    float s = 0.f;
    float h;
    h = bf2f((unsigned short)a8[0]) + bf2f((unsigned short)b8[0]) + bb0.x;
    s = fmaf(fmaxf(h, 0.f), w0.x, s);
    h = bf2f((unsigned short)a8[1]) + bf2f((unsigned short)b8[1]) + bb0.y;
    s = fmaf(fmaxf(h, 0.f), w0.y, s);
    h = bf2f((unsigned short)a8[2]) + bf2f((unsigned short)b8[2]) + bb0.z;
    s = fmaf(fmaxf(h, 0.f), w0.z, s);
    h = bf2f((unsigned short)a8[3]) + bf2f((unsigned short)b8[3]) + bb0.w;
    s = fmaf(fmaxf(h, 0.f), w0.w, s);
    h = bf2f((unsigned short)a8[4]) + bf2f((unsigned short)b8[4]) + bb1.x;
    s = fmaf(fmaxf(h, 0.f), w1.x, s);
    h = bf2f((unsigned short)a8[5]) + bf2f((unsigned short)b8[5]) + bb1.y;
    s = fmaf(fmaxf(h, 0.f), w1.y, s);
    h = bf2f((unsigned short)a8[6]) + bf2f((unsigned short)b8[6]) + bb1.z;
    s = fmaf(fmaxf(h, 0.f), w1.z, s);
    h = bf2f((unsigned short)a8[7]) + bf2f((unsigned short)b8[7]) + bb1.w;
    s = fmaf(fmaxf(h, 0.f), w1.w, s);
    s += __shfl_xor(s, 1);
    s += __shfl_xor(s, 2);
    s += __shfl_xor(s, 4);
    s += __shfl_xor(s, 8);
    s += __shfl_xor(s, 16);
    s += __shfl_xor(s, 32);
    if (lane == 0) outp[r] = s + b2[c];
}

// ---------------------------------------------------------------------------
extern "C" void kernel_launch(void* const* d_in, const int* in_sizes, int n_in,
                              void* d_out, int out_size, void* d_ws, size_t ws_size,
                              hipStream_t stream) {
    const float* x   = (const float*)d_in[0];
    const int* ei    = (const int*)d_in[1];
    const int* ddb   = (const int*)d_in[2];
    const int* ecl   = (const int*)d_in[3];
    const float* Wg1 = (const float*)d_in[5];
    const float* bg1 = (const float*)d_in[6];
    const float* Wg2 = (const float*)d_in[7];
    const float* bg2 = (const float*)d_in[8];
    const float* W1  = (const float*)d_in[9];
    const float* b1  = (const float*)d_in[10];
    const float* W2  = (const float*)d_in[11];
    const float* b2  = (const float*)d_in[12];
    float* outp = (float*)d_out;

    const size_t NC = (size_t)N_NODES * CDIM;                      // 5.12M elems
    const size_t HRES = (size_t)NUM_DRUGS * HN * sizeof(float);    // 67.1 MB reserved
    // Region 0 (inside reserved extent; all dead before the H GEMM writes Hbf):
    // Hbf (bf16, 33.6 MB) overlaps t2bf/t1bf/h1bf — all dead at H-GEMM time.
    char* r0 = (char*)d_ws;
    unsigned short* Hbf   = (unsigned short*)d_ws;
    unsigned short* t2bf  = (unsigned short*)r0;                   // 10.24 MB
    unsigned short* t1bf  = (unsigned short*)(r0 + 20480000);
    unsigned short* h2bf  = t1bf;
    unsigned short* h1bf  = (unsigned short*)(r0 + 30720000);      // single bf16
    unsigned short* xhi   = h1bf;                                  // dead before agg1 writes
    unsigned short* xlo   = (unsigned short*)(r0 + 40960000);
    char* p = r0 + 51200000;
    auto alloc = [&](size_t bytes) {
        char* r = p;
        p += (bytes + 255) & ~size_t(255);
        return (void*)r;
    };
    float* dinv    = (float*)alloc(sizeof(float) * N_NODES);
    int* cur_d     = (int*)alloc(sizeof(int) * NUM_DRUGS * STRD);
    int* cur_p     = (int*)alloc(sizeof(int) * N_NODES * STRP);
    int* adj_drug  = (int*)alloc(sizeof(int) * NUM_DRUGS * ELLD);
    int* adj_prot  = (int*)alloc(sizeof(int) * (size_t)N_NODES * ELLP);
    // Region 1 (after reserved extent): buffers the H GEMM reads
    p = (char*)d_ws + ((HRES + 255) & ~size_t(255));
    unsigned short* Gb    = (unsigned short*)alloc(2 * NUM_DRUGS * CDIM);
    unsigned short* wg1Th = (unsigned short*)alloc(2 * CDIM * CDIM);
    unsigned short* wg1Tl = (unsigned short*)alloc(2 * CDIM * CDIM);
    unsigned short* wg2Th = (unsigned short*)alloc(2 * CDIM * CDIM);
    unsigned short* wg2Tl = (unsigned short*)alloc(2 * CDIM * CDIM);
    unsigned short* W1Th  = (unsigned short*)alloc(2 * (size_t)N_CL * HID * HID);
    unsigned short* W1Tl  = (unsigned short*)alloc(2 * (size_t)N_CL * HID * HID);

    // zero counters (fill range in prep_all depends on it in stream order)
    zero_counts<<<(N_NODES + 255) / 256, 256, 0, stream>>>(cur_d, cur_p);
    // fused prep: ELL fill + x split + Wg transposes + W1 transpose
    prep_all<<<NB_FILL + NB_T64 + NB_TWG + NB_SPLIT, 256, 0, stream>>>(
        ei, cur_d, adj_drug, cur_p, adj_prot,
        x, xhi, xlo, Wg1, Wg2, wg1Th, wg1Tl, wg2Th, wg2Tl, W1, W1Th, W1Tl);
    // GCN layer 1: A split (x), bf16-only output (t1bf); XCD-paired rows;
    // dinv fused as 79 extra blocks.
    gemm_mfma<64, 128, 2, 1><<<dim3(NB_GNODE + 79, 1), 256, 0, stream>>>(
        xhi, xlo, wg1Th, wg1Tl, nullptr, t1bf, N_NODES, CDIM, CDIM,
        NB_GNODE, cur_d, cur_p, dinv);
    aggregate1<<<NB_AGG_D + NB_AGG_P, 256, 0, stream>>>(
        t1bf, cur_d, adj_drug, cur_p, adj_prot, dinv, bg1, h1bf);
    // GCN layer 2: A SINGLE bf16 (h1bf), 2-MFMA path; bf16-only output (t2bf).
    gemm_mfma<64, 128, 2, 0><<<dim3(NB_GNODE, 1), 256, 0, stream>>>(
        h1bf, nullptr, wg2Th, wg2Tl, nullptr, t2bf, N_NODES, CDIM, CDIM,
        NB_GNODE, nullptr, nullptr, nullptr);
    aggregate2p<<<(N_PROT * 64 + 255) / 256, 256, 0, stream>>>(
        t2bf, cur_p, adj_prot, dinv, bg2, h2bf);
    // pool (bf16 gather, 4 waves/drug) -> single-bf16 graph embeddings
    pool_drugs<<<NUM_DRUGS, 256, 0, stream>>>(h2bf, Gb, cur_d, adj_drug);
    // MLP precompute: Hbf[2048, 8192] (bf16) = Gb @ W1cat; A single bf16,
    // 48KB LDS dbuf -> 3 blocks/CU; XCD-swizzled (16,64) grid
    gemm_mfma<128, 128, 1, 0><<<dim3(NUM_DRUGS / 128, HN / 128), 256, 0, stream>>>(
        Gb, nullptr, W1Th, W1Tl, nullptr, Hbf, NUM_DRUGS, CDIM, HN,
        NUM_DRUGS / 128, nullptr, nullptr, nullptr);
    // epilogue: gather 2 Hbf rows per batch row, relu+dot, direct store
    mlp_out<<<(BATCH * 64) / 256, 256, 0, stream>>>(Hbf, ddb, ecl, b1, W2, b2, outp);
}

// Round 12
// 226.956 us; speedup vs baseline: 1.1005x; 1.0275x over previous
//
#include <hip/hip_runtime.h>
#include <hip/hip_bf16.h>

// Problem constants (fixed by reference)
#define N_NODES 20000
#define NUM_DRUGS 2048
#define N_PROT (N_NODES - NUM_DRUGS)
#define NUM_DPI 200000
#define E2 400000          // 2*NUM_DPI directed edges
#define CDIM 256           // IN_C == EMB == 256
#define HID 512
#define N_CL 8
#define BATCH 16384
#define HN 8192            // H cols = 8 experts x 2 halves x 512

#define STRD 32            // drug counter padding (ints) = 1 line per counter
#define STRP 16            // protein counter padding
#define ELLD 192           // drug ELL stride (mean deg 97.7, +9.5 sigma)
#define ELLP 48            // protein ELL stride (mean deg 11.1, +11 sigma)

// fused-prep block ranges
#define NB_FILL 782        // ELL fill: 200000 / 256
#define NB_T64 512         // W1 transpose: 4 x 8 x 16
#define NB_TWG 32          // Wg1/Wg2 transpose: 4 x 4 x 2
#define NB_SPLIT 20000     // x convert: 5.12M / 256

// node-GEMM tiling (BM=64): 313 row tiles; XCD-paired grid of 640 (8 x 80)
#define MT_NODE 313
#define NB_GNODE 640       // 8 XCDs x 80 slots (40 row-panels x 2 col-halves; 14 idle)

// aggregate1 grid split
#define NB_AGG_D NUM_DRUGS              // 1 block per drug (4 waves)
#define NB_AGG_P ((N_PROT + 3) / 4)     // 4 proteins per block (1 wave each)

typedef __attribute__((ext_vector_type(8))) short short8;   // 8 bf16 (MFMA A/B frag)
typedef __attribute__((ext_vector_type(4))) float floatx4;  // MFMA C/D frag

__device__ inline unsigned short f2bf(float f) {
    unsigned u = __float_as_uint(f);
    u += 0x7fff + ((u >> 16) & 1);   // RNE
    return (unsigned short)(u >> 16);
}
__device__ inline float bf2f(unsigned short h) {
    return __uint_as_float((unsigned)h << 16);
}
__device__ inline void split2(float v, unsigned short& h, unsigned short& l) {
    h = f2bf(v);
    l = f2bf(v - bf2f(h));
}
__device__ inline void gload16(const void* g, void* l) {
    __builtin_amdgcn_global_load_lds(
        (const __attribute__((address_space(1))) void*)g,
        (__attribute__((address_space(3))) void*)l, 16, 0, 0);
}
__device__ inline float4 f4fma(float4 v, float s, float4 a) {
    a.x = fmaf(v.x, s, a.x); a.y = fmaf(v.y, s, a.y);
    a.z = fmaf(v.z, s, a.z); a.w = fmaf(v.w, s, a.w);
    return a;
}
__device__ inline float4 bf4(const unsigned short* p) {
    ushort4 q = *(const ushort4*)p;
    return make_float4(bf2f(q.x), bf2f(q.y), bf2f(q.z), bf2f(q.w));
}

// ---------------------------------------------------------------------------
// counter zeroing (tiny dispatch)
__global__ void zero_counts(int* cur_d, int* cur_p) {
    int i = blockIdx.x * blockDim.x + threadIdx.x;
    if (i < N_NODES) cur_p[i * STRP] = 0;
    if (i < NUM_DRUGS) cur_d[i * STRD] = 0;
}

// ---------------------------------------------------------------------------
// Fused prep: ELL fill | W1 transpose (SINGLE bf16) | Wg1/Wg2 transpose-split |
// x convert (SINGLE bf16). Counters zeroed by the preceding zero_counts.
__global__ __launch_bounds__(256) void prep_all(
        const int* __restrict__ ei, int* __restrict__ cur_d,
        int* __restrict__ adj_drug, int* __restrict__ cur_p,
        int* __restrict__ adj_prot,
        const float* __restrict__ x, unsigned short* __restrict__ xbf,
        const float* __restrict__ Wg1, const float* __restrict__ Wg2,
        unsigned short* __restrict__ wg1Th, unsigned short* __restrict__ wg1Tl,
        unsigned short* __restrict__ wg2Th, unsigned short* __restrict__ wg2Tl,
        const float* __restrict__ W1, unsigned short* __restrict__ W1Tb) {
    __shared__ float ld[64 * 65];
    int b = blockIdx.x;
    int t = threadIdx.x;
    int tx = t & 63, ty = t >> 6;
    if (b < NB_FILL) {
        int e = b * 256 + t;
        if (e < NUM_DPI) {
            int d = ei[e];
            int p = ei[E2 + e];
            int posd = atomicAdd(&cur_d[d * STRD], 1);
            int posp = atomicAdd(&cur_p[p * STRP], 1);
            if (posd < ELLD) adj_drug[d * ELLD + posd] = p;   // clamp
            if (posp < ELLP) adj_prot[(size_t)p * ELLP + posp] = d;
        }
        return;
    }
    b -= NB_FILL;
    if (b < NB_T64) {
        // W1 [16 slabs][256][512] -> W1cat^T [8192][256] single bf16
        int m = b >> 5;
        int k0 = (b & 3) * 64, n0 = ((b >> 2) & 7) * 64;
        const float* Wm = W1 + (size_t)m * CDIM * HID;
#pragma unroll
        for (int rr = 0; rr < 16; rr++) {
            int kl = rr * 4 + ty;
            ld[tx * 65 + kl] = Wm[(size_t)(k0 + kl) * HID + n0 + tx];
        }
        __syncthreads();
        size_t obase = (size_t)m * HID * CDIM;
#pragma unroll
        for (int rr = 0; rr < 16; rr++) {
            int nl = rr * 4 + ty;
            size_t o = obase + (size_t)(n0 + nl) * CDIM + k0 + tx;
            W1Tb[o] = f2bf(ld[nl * 65 + tx]);
        }
        return;
    }
    b -= NB_T64;
    if (b < NB_TWG) {
        // Wg1/Wg2 [256][256] -> transposed split bf16
        const float* W = (b >> 4) ? Wg2 : Wg1;
        unsigned short* hi = (b >> 4) ? wg2Th : wg1Th;
        unsigned short* lo = (b >> 4) ? wg2Tl : wg1Tl;
        int k0 = (b & 3) * 64, n0 = ((b >> 2) & 3) * 64;
#pragma unroll
        for (int rr = 0; rr < 16; rr++) {
            int kl = rr * 4 + ty;
            ld[tx * 65 + kl] = W[(size_t)(k0 + kl) * CDIM + n0 + tx];
        }
        __syncthreads();
#pragma unroll
        for (int rr = 0; rr < 16; rr++) {
            int nl = rr * 4 + ty;
            float v = ld[nl * 65 + tx];
            unsigned short h, l;
            split2(v, h, l);
            size_t o = (size_t)(n0 + nl) * CDIM + k0 + tx;
            hi[o] = h;
            lo[o] = l;
        }
        return;
    }
    b -= NB_TWG;
    {   // x convert: exactly NB_SPLIT blocks cover 5.12M elems (single bf16)
        int i = b * 256 + t;
        xbf[i] = f2bf(x[i]);
    }
}

// ---------------------------------------------------------------------------
// bf16 MFMA GEMM: C[M,N] = A[M,K] @ B[K,N], B passed as B^T ([N][K]).
// ASPLIT/BSPLIT select split (hi+lo) vs single-bf16 operands:
//   gemm1/gemm2 <64,128,SWZ2,A=0,B=1>: 2 MFMA, 40KB dbuf -> 4 blocks/CU.
//   H GEMM <128,128,SWZ1,A=0,B=0>: pure bf16, 1 MFMA/frag, 32KB dbuf ->
//     5 blocks/CU at full 128^2 intensity (the R5/R6 target quadrant,
//     reached by byte reduction instead of tile shrink).
// SWZ=1: XCD k owns col-tiles [8k,8k+8) of the (16,64) grid.
// SWZ=2: XCD-paired rows on (640,1): xcd=id&7, k=id>>3, by=k&1,
//   bx=xcd*40+(k>>1); bx>=313 idle. Bijective onto [0,313)x[0,2).
// Blocks with blockIdx.x >= mTiles run the fused dinv computation instead.
template <int BM, int BN, int SWZ, int ASPLIT, int BSPLIT>
__global__ __launch_bounds__(256) void gemm_mfma(
        const unsigned short* __restrict__ Ahi, const unsigned short* __restrict__ Alo,
        const unsigned short* __restrict__ BThi, const unsigned short* __restrict__ BTlo,
        float* __restrict__ C, unsigned short* __restrict__ Cbf,
        int M, int K, int N, int mTiles,
        const int* __restrict__ cur_d, const int* __restrict__ cur_p,
        float* __restrict__ dinv) {
    if ((int)blockIdx.x >= mTiles) {
        int i = (((int)blockIdx.x - mTiles) * (int)gridDim.y + (int)blockIdx.y) * 256
                + (int)threadIdx.x;
        if (i < N_NODES) {
            int deg = (i < NUM_DRUGS) ? cur_d[i * STRD] : cur_p[i * STRP];
            dinv[i] = rsqrtf((float)(deg + 1));
        }
        return;
    }
    constexpr int MI = BM / 32;           // acc row-frags per wave
    constexpr int NJ = BN / 32;           // acc col-frags per wave
    constexpr int ASZ = ASPLIT ? BM * 32 : 8;
    constexpr int BSZ = BSPLIT ? BN * 32 : 8;
    __shared__ unsigned short sAh[2][BM * 32], sAl[2][ASZ];
    __shared__ unsigned short sBh[2][BN * 32], sBl[2][BSZ];
    int t = threadIdx.x;
    int wv = t >> 6, lane = t & 63, quad = lane >> 4, l15 = lane & 15;
    int bx = blockIdx.x, by = blockIdx.y;
    if constexpr (SWZ == 1) {
        int w = by * 16 + bx;
        int xcd = w & 7, j = w >> 3;
        bx = j & 15;
        by = xcd * 8 + (j >> 4);
    }
    if constexpr (SWZ == 2) {
        int id = bx;
        int xcd = id & 7, k = id >> 3;    // k in [0,80)
        by = k & 1;
        bx = xcd * 40 + (k >> 1);
        if (bx >= MT_NODE) return;        // 14 idle pad blocks
    }
    int m0 = bx * BM, n0 = by * BN;
    int m0w = (wv >> 1) * (BM / 2), n0w = (wv & 1) * (BN / 2);
    floatx4 zero = {0.f, 0.f, 0.f, 0.f};
    floatx4 acc[MI][NJ];
#pragma unroll
    for (int i = 0; i < MI; i++)
#pragma unroll
        for (int j = 0; j < NJ; j++) acc[i][j] = zero;

    auto STAGE = [&](int buf, int kk) {
#pragma unroll
        for (int s = t; s < BM * 4; s += 256) {   // A slots
            int row = s >> 2, pos = s & 3;
            int ch = pos ^ ((row >> 1) & 3);      // XOR-swizzled chunk
            int arow = m0 + row; if (arow > M - 1) arow = M - 1;
            size_t aoff = (size_t)arow * K + kk + ch * 8;
            gload16(Ahi + aoff, &sAh[buf][s * 8]);
            if constexpr (ASPLIT) gload16(Alo + aoff, &sAl[buf][s * 8]);
        }
#pragma unroll
        for (int s = t; s < BN * 4; s += 256) {   // B slots
            int row = s >> 2, pos = s & 3;
            int ch = pos ^ ((row >> 1) & 3);
            int brow = n0 + row; if (brow > N - 1) brow = N - 1;
            size_t boff = (size_t)brow * K + kk + ch * 8;
            gload16(BThi + boff, &sBh[buf][s * 8]);
            if constexpr (BSPLIT) gload16(BTlo + boff, &sBl[buf][s * 8]);
        }
    };

    int nk = K >> 5;
    STAGE(0, 0);
    asm volatile("s_waitcnt vmcnt(0)" ::: "memory");
    __builtin_amdgcn_s_barrier();
    int cur = 0;
    for (int it = 0; it < nk; ++it) {
        if (it + 1 < nk) STAGE(cur ^ 1, (it + 1) << 5);   // prefetch next tile
        short8 ah[MI], al[MI], bh[NJ], bl[NJ];
        int posq = quad ^ ((l15 >> 1) & 3);
#pragma unroll
        for (int i = 0; i < MI; i++) {
            int sl = (m0w + i * 16 + l15) * 4 + posq;
            ah[i] = *(const short8*)&sAh[cur][sl * 8];
            if constexpr (ASPLIT) al[i] = *(const short8*)&sAl[cur][sl * 8];
        }
#pragma unroll
        for (int j = 0; j < NJ; j++) {
            int sl = (n0w + j * 16 + l15) * 4 + posq;
            bh[j] = *(const short8*)&sBh[cur][sl * 8];
            if constexpr (BSPLIT) bl[j] = *(const short8*)&sBl[cur][sl * 8];
        }
#pragma unroll
        for (int i = 0; i < MI; i++)
#pragma unroll
            for (int j = 0; j < NJ; j++) {
                acc[i][j] = __builtin_amdgcn_mfma_f32_16x16x32_bf16(ah[i], bh[j], acc[i][j], 0, 0, 0);
                if constexpr (BSPLIT)
                    acc[i][j] = __builtin_amdgcn_mfma_f32_16x16x32_bf16(ah[i], bl[j], acc[i][j], 0, 0, 0);
                if constexpr (ASPLIT)
                    acc[i][j] = __builtin_amdgcn_mfma_f32_16x16x32_bf16(al[i], bh[j], acc[i][j], 0, 0, 0);
            }
        if (it + 1 < nk) {
            asm volatile("s_waitcnt vmcnt(0)" ::: "memory");  // next tile landed
            __builtin_amdgcn_s_barrier();                     // all reads of cur done
            cur ^= 1;
        }
    }
#pragma unroll
    for (int i = 0; i < MI; i++) {
        int gr = m0 + m0w + i * 16 + quad * 4;
#pragma unroll
        for (int r = 0; r < 4; r++) {
            if (gr + r < M) {
#pragma unroll
                for (int j = 0; j < NJ; j++) {
                    size_t o = (size_t)(gr + r) * N + n0 + n0w + j * 16 + l15;
                    float v = acc[i][j][r];
                    if (C) C[o] = v;
                    if (Cbf) Cbf[o] = f2bf(v);
                }
            }
        }
    }
}

// ---------------------------------------------------------------------------
// Layer-1 GCN aggregate — reads bf16 (t1bf), writes h1 single bf16.
__global__ __launch_bounds__(256) void aggregate1(const unsigned short* __restrict__ tmpbf,
                                                  const int* __restrict__ cur_d,
                                                  const int* __restrict__ adj_drug,
                                                  const int* __restrict__ cur_p,
                                                  const int* __restrict__ adj_prot,
                                                  const float* __restrict__ dinv,
                                                  const float* __restrict__ bias,
                                                  unsigned short* __restrict__ outbf) {
    __shared__ float4 red[4][64];
    int b = blockIdx.x;
    int lane = threadIdx.x & 63;
    if (b < NB_AGG_D) {
        int d = b;
        int w = threadIdx.x >> 6;
        const int* adj = adj_drug + (size_t)d * ELLD;
        int ecnt = cur_d[d * STRD];
        int e = ecnt < ELLD ? ecnt : ELLD;
        float4 a0 = make_float4(0.f, 0.f, 0.f, 0.f);
        float4 a1 = a0, a2 = a0, a3 = a0;
        int idx = w;
        for (; idx + 12 < e; idx += 16) {
            int j0 = adj[idx], j1 = adj[idx + 4], j2 = adj[idx + 8], j3 = adj[idx + 12];
            float d0 = dinv[j0], d1 = dinv[j1], d2 = dinv[j2], d3 = dinv[j3];
            float4 v0 = bf4(&tmpbf[(size_t)j0 * CDIM + lane * 4]);
            float4 v1 = bf4(&tmpbf[(size_t)j1 * CDIM + lane * 4]);
            float4 v2 = bf4(&tmpbf[(size_t)j2 * CDIM + lane * 4]);
            float4 v3 = bf4(&tmpbf[(size_t)j3 * CDIM + lane * 4]);
            a0 = f4fma(v0, d0, a0);
            a1 = f4fma(v1, d1, a1);
            a2 = f4fma(v2, d2, a2);
            a3 = f4fma(v3, d3, a3);
        }
        for (; idx < e; idx += 4) {
            int j = adj[idx];
            a0 = f4fma(bf4(&tmpbf[(size_t)j * CDIM + lane * 4]), dinv[j], a0);
        }
        a0.x = (a0.x + a1.x) + (a2.x + a3.x);
        a0.y = (a0.y + a1.y) + (a2.y + a3.y);
        a0.z = (a0.z + a1.z) + (a2.z + a3.z);
        a0.w = (a0.w + a1.w) + (a2.w + a3.w);
        red[w][lane] = a0;
        __syncthreads();
        if (w == 0) {
            float di = dinv[d];
            float4 r0 = red[0][lane], r1 = red[1][lane], r2 = red[2][lane], r3 = red[3][lane];
            float4 self = bf4(&tmpbf[(size_t)d * CDIM + lane * 4]);
            float4 acc;
            acc.x = (r0.x + r1.x) + (r2.x + r3.x) + self.x * di;
            acc.y = (r0.y + r1.y) + (r2.y + r3.y) + self.y * di;
            acc.z = (r0.z + r1.z) + (r2.z + r3.z) + self.z * di;
            acc.w = (r0.w + r1.w) + (r2.w + r3.w) + self.w * di;
            float4 bv = ((const float4*)bias)[lane];
            ushort4 o;
            o.x = f2bf(fmaxf(fmaf(acc.x, di, bv.x), 0.f));
            o.y = f2bf(fmaxf(fmaf(acc.y, di, bv.y), 0.f));
            o.z = f2bf(fmaxf(fmaf(acc.z, di, bv.z), 0.f));
            o.w = f2bf(fmaxf(fmaf(acc.w, di, bv.w), 0.f));
            *(ushort4*)&outbf[(size_t)d * CDIM + lane * 4] = o;
        }
        return;
    }
    // protein destinations: one wave per node, bf16 gathers
    int i = NUM_DRUGS + (b - NB_AGG_D) * 4 + (threadIdx.x >> 6);
    if (i >= N_NODES) return;
    float di = dinv[i];
    float4 a0 = make_float4(0.f, 0.f, 0.f, 0.f);
    float4 a1 = a0, a2 = a0, a3 = a0;
    const int* adj = adj_prot + (size_t)i * ELLP;
    int e = cur_p[i * STRP];
    int idx = 0;
    for (; idx + 4 <= e; idx += 4) {
        int j0 = adj[idx + 0], j1 = adj[idx + 1];
        int j2 = adj[idx + 2], j3 = adj[idx + 3];
        float d0 = dinv[j0], d1 = dinv[j1], d2 = dinv[j2], d3 = dinv[j3];
        float4 v0 = bf4(&tmpbf[(size_t)j0 * CDIM + lane * 4]);
        float4 v1 = bf4(&tmpbf[(size_t)j1 * CDIM + lane * 4]);
        float4 v2 = bf4(&tmpbf[(size_t)j2 * CDIM + lane * 4]);
        float4 v3 = bf4(&tmpbf[(size_t)j3 * CDIM + lane * 4]);
        a0 = f4fma(v0, d0, a0);
        a1 = f4fma(v1, d1, a1);
        a2 = f4fma(v2, d2, a2);
        a3 = f4fma(v3, d3, a3);
    }
    for (; idx < e; idx++) {
        int j = adj[idx];
        a0 = f4fma(bf4(&tmpbf[(size_t)j * CDIM + lane * 4]), dinv[j], a0);
    }
    float4 self = bf4(&tmpbf[(size_t)i * CDIM + lane * 4]);
    float4 acc;
    acc.x = (a0.x + a1.x) + (a2.x + a3.x) + self.x * di;
    acc.y = (a0.y + a1.y) + (a2.y + a3.y) + self.y * di;
    acc.z = (a0.z + a1.z) + (a2.z + a3.z) + self.z * di;
    acc.w = (a0.w + a1.w) + (a2.w + a3.w) + self.w * di;
    float4 bv = ((const float4*)bias)[lane];
    ushort4 o;
    o.x = f2bf(fmaxf(fmaf(acc.x, di, bv.x), 0.f));
    o.y = f2bf(fmaxf(fmaf(acc.y, di, bv.y), 0.f));
    o.z = f2bf(fmaxf(fmaf(acc.z, di, bv.z), 0.f));
    o.w = f2bf(fmaxf(fmaf(acc.w, di, bv.w), 0.f));
    *(ushort4*)&outbf[(size_t)i * CDIM + lane * 4] = o;
}

// Layer-2 GCN aggregate, PROTEIN rows only, bf16 gathers (t2bf).
__global__ __launch_bounds__(256) void aggregate2p(const unsigned short* __restrict__ t2bf,
                                                   const int* __restrict__ cur_p,
                                                   const int* __restrict__ adj_prot,
                                                   const float* __restrict__ dinv,
                                                   const float* __restrict__ bias,
                                                   unsigned short* __restrict__ h2bf) {
    int w = (blockIdx.x * blockDim.x + threadIdx.x) >> 6;
    int lane = threadIdx.x & 63;
    if (w >= N_PROT) return;
    int i = NUM_DRUGS + w;
    float di = dinv[i];
    float4 a0 = make_float4(0.f, 0.f, 0.f, 0.f);
    float4 a1 = a0, a2 = a0, a3 = a0;
    const int* adj = adj_prot + (size_t)i * ELLP;
    int e = cur_p[i * STRP];
    int idx = 0;
    for (; idx + 4 <= e; idx += 4) {
        int j0 = adj[idx + 0], j1 = adj[idx + 1];
        int j2 = adj[idx + 2], j3 = adj[idx + 3];
        float d0 = dinv[j0], d1 = dinv[j1], d2 = dinv[j2], d3 = dinv[j3];
        float4 v0 = bf4(&t2bf[(size_t)j0 * CDIM + lane * 4]);
        float4 v1 = bf4(&t2bf[(size_t)j1 * CDIM + lane * 4]);
        float4 v2 = bf4(&t2bf[(size_t)j2 * CDIM + lane * 4]);
        float4 v3 = bf4(&t2bf[(size_t)j3 * CDIM + lane * 4]);
        a0 = f4fma(v0, d0, a0);
        a1 = f4fma(v1, d1, a1);
        a2 = f4fma(v2, d2, a2);
        a3 = f4fma(v3, d3, a3);
    }
    for (; idx < e; idx++) {
        int j = adj[idx];
        a0 = f4fma(bf4(&t2bf[(size_t)j * CDIM + lane * 4]), dinv[j], a0);
    }
    float4 self = bf4(&t2bf[(size_t)i * CDIM + lane * 4]);
    float4 acc;
    acc.x = (a0.x + a1.x) + (a2.x + a3.x) + self.x * di;
    acc.y = (a0.y + a1.y) + (a2.y + a3.y) + self.y * di;
    acc.z = (a0.z + a1.z) + (a2.z + a3.z) + self.z * di;
    acc.w = (a0.w + a1.w) + (a2.w + a3.w) + self.w * di;
    float4 bv = ((const float4*)bias)[lane];
    ushort4 o;
    o.x = f2bf(fmaxf(fmaf(acc.x, di, bv.x), 0.f));
    o.y = f2bf(fmaxf(fmaf(acc.y, di, bv.y), 0.f));
    o.z = f2bf(fmaxf(fmaf(acc.z, di, bv.z), 0.f));
    o.w = f2bf(fmaxf(fmaf(acc.w, di, bv.w), 0.f));
    *(ushort4*)&h2bf[(size_t)i * CDIM + lane * 4] = o;
}

// scatter-mean pool from bf16 h2 -> single bf16 graph embeddings.
__global__ __launch_bounds__(256) void pool_drugs(const unsigned short* __restrict__ h2bf,
                                                  unsigned short* __restrict__ Gb,
                                                  const int* __restrict__ cur_d,
                                                  const int* __restrict__ adj_drug) {
    __shared__ float4 red[4][64];
    int d = blockIdx.x;
    int w = threadIdx.x >> 6, lane = threadIdx.x & 63;
    const int* adj = adj_drug + (size_t)d * ELLD;
    int ecnt = cur_d[d * STRD];
    int e = ecnt < ELLD ? ecnt : ELLD;
    float4 a0 = make_float4(0.f, 0.f, 0.f, 0.f);
    float4 a1 = a0, a2 = a0, a3 = a0;
    int idx = w;
    for (; idx + 12 < e; idx += 16) {
        int j0 = adj[idx], j1 = adj[idx + 4], j2 = adj[idx + 8], j3 = adj[idx + 12];
        float4 v0 = bf4(&h2bf[(size_t)j0 * CDIM + lane * 4]);
        float4 v1 = bf4(&h2bf[(size_t)j1 * CDIM + lane * 4]);
        float4 v2 = bf4(&h2bf[(size_t)j2 * CDIM + lane * 4]);
        float4 v3 = bf4(&h2bf[(size_t)j3 * CDIM + lane * 4]);
        a0.x += v0.x; a0.y += v0.y; a0.z += v0.z; a0.w += v0.w;
        a1.x += v1.x; a1.y += v1.y; a1.z += v1.z; a1.w += v1.w;
        a2.x += v2.x; a2.y += v2.y; a2.z += v2.z; a2.w += v2.w;
        a3.x += v3.x; a3.y += v3.y; a3.z += v3.z; a3.w += v3.w;
    }
    for (; idx < e; idx += 4) {
        float4 v = bf4(&h2bf[(size_t)adj[idx] * CDIM + lane * 4]);
        a0.x += v.x; a0.y += v.y; a0.z += v.z; a0.w += v.w;
    }
    a0.x = (a0.x + a1.x) + (a2.x + a3.x);
    a0.y = (a0.y + a1.y) + (a2.y + a3.y);
    a0.z = (a0.z + a1.z) + (a2.z + a3.z);
    a0.w = (a0.w + a1.w) + (a2.w + a3.w);
    red[w][lane] = a0;
    __syncthreads();
    if (w == 0) {
        float4 r0 = red[0][lane], r1 = red[1][lane], r2 = red[2][lane], r3 = red[3][lane];
        float4 acc;
        acc.x = (r0.x + r1.x) + (r2.x + r3.x);
        acc.y = (r0.y + r1.y) + (r2.y + r3.y);
        acc.z = (r0.z + r1.z) + (r2.z + r3.z);
        acc.w = (r0.w + r1.w) + (r2.w + r3.w);
        float sc = 1.f / (float)(ecnt > 1 ? ecnt : 1);
        ushort4 o;
        o.x = f2bf(acc.x * sc);
        o.y = f2bf(acc.y * sc);
        o.z = f2bf(acc.z * sc);
        o.w = f2bf(acc.w * sc);
        *(ushort4*)&Gb[(size_t)d * CDIM + lane * 4] = o;
    }
}

// ---------------------------------------------------------------------------
// MLP epilogue: out[r] = sum_n relu(H[d0][2c*512+n] + H[d1][(2c+1)*512+n]
//                                   + b1[c][n]) * W2[c][n] + b2[c]
__global__ __launch_bounds__(256) void mlp_out(const unsigned short* __restrict__ Hbf,
                                               const int* __restrict__ ddb,
                                               const int* __restrict__ ecl,
                                               const float* __restrict__ b1,
                                               const float* __restrict__ W2,
                                               const float* __restrict__ b2,
                                               float* __restrict__ outp) {
    int r = (blockIdx.x * blockDim.x + threadIdx.x) >> 6;
    int lane = threadIdx.x & 63;
    if (r >= BATCH) return;
    int c = ecl[r];
    int d0 = ddb[r], d1 = ddb[BATCH + r];
    int n = lane * 8;
    const unsigned short* h0 = Hbf + (size_t)d0 * HN + (size_t)(c * 2) * HID + n;
    const unsigned short* h1 = Hbf + (size_t)d1 * HN + (size_t)(c * 2 + 1) * HID + n;
    const float* b1e = b1 + (size_t)c * HID + n;
    const float* w2e = W2 + (size_t)c * HID + n;
    short8 a8 = *(const short8*)h0;
    short8 b8 = *(const short8*)h1;
    float4 bb0 = *(const float4*)(b1e);
    float4 bb1 = *(const float4*)(b1e + 4);
    float4 w0 = *(const float4*)(w2e);
    float4 w1 = *(const float4*)(w2e + 4);
    float s = 0.f;
    float h;
    h = bf2f((unsigned short)a8[0]) + bf2f((unsigned short)b8[0]) + bb0.x;
    s = fmaf(fmaxf(h, 0.f), w0.x, s);
    h = bf2f((unsigned short)a8[1]) + bf2f((unsigned short)b8[1]) + bb0.y;
    s = fmaf(fmaxf(h, 0.f), w0.y, s);
    h = bf2f((unsigned short)a8[2]) + bf2f((unsigned short)b8[2]) + bb0.z;
    s = fmaf(fmaxf(h, 0.f), w0.z, s);
    h = bf2f((unsigned short)a8[3]) + bf2f((unsigned short)b8[3]) + bb0.w;
    s = fmaf(fmaxf(h, 0.f), w0.w, s);
    h = bf2f((unsigned short)a8[4]) + bf2f((unsigned short)b8[4]) + bb1.x;
    s = fmaf(fmaxf(h, 0.f), w1.x, s);
    h = bf2f((unsigned short)a8[5]) + bf2f((unsigned short)b8[5]) + bb1.y;
    s = fmaf(fmaxf(h, 0.f), w1.y, s);
    h = bf2f((unsigned short)a8[6]) + bf2f((unsigned short)b8[6]) + bb1.z;
    s = fmaf(fmaxf(h, 0.f), w1.z, s);
    h = bf2f((unsigned short)a8[7]) + bf2f((unsigned short)b8[7]) + bb1.w;
    s = fmaf(fmaxf(h, 0.f), w1.w, s);
    s += __shfl_xor(s, 1);
    s += __shfl_xor(s, 2);
    s += __shfl_xor(s, 4);
    s += __shfl_xor(s, 8);
    s += __shfl_xor(s, 16);
    s += __shfl_xor(s, 32);
    if (lane == 0) outp[r] = s + b2[c];
}

// ---------------------------------------------------------------------------
extern "C" void kernel_launch(void* const* d_in, const int* in_sizes, int n_in,
                              void* d_out, int out_size, void* d_ws, size_t ws_size,
                              hipStream_t stream) {
    const float* x   = (const float*)d_in[0];
    const int* ei    = (const int*)d_in[1];
    const int* ddb   = (const int*)d_in[2];
    const int* ecl   = (const int*)d_in[3];
    const float* Wg1 = (const float*)d_in[5];
    const float* bg1 = (const float*)d_in[6];
    const float* Wg2 = (const float*)d_in[7];
    const float* bg2 = (const float*)d_in[8];
    const float* W1  = (const float*)d_in[9];
    const float* b1  = (const float*)d_in[10];
    const float* W2  = (const float*)d_in[11];
    const float* b2  = (const float*)d_in[12];
    float* outp = (float*)d_out;

    const size_t HRES = (size_t)NUM_DRUGS * HN * sizeof(float);    // 67.1 MB reserved
    // Region 0 (inside reserved extent; all dead before the H GEMM writes Hbf):
    // Hbf (bf16, 33.6 MB) overlaps t2bf/t1bf/h1bf/xbf — all dead at H-GEMM time.
    char* r0 = (char*)d_ws;
    unsigned short* Hbf   = (unsigned short*)d_ws;
    unsigned short* t2bf  = (unsigned short*)r0;                   // 10.24 MB
    unsigned short* t1bf  = (unsigned short*)(r0 + 20480000);
    unsigned short* h2bf  = t1bf;
    unsigned short* h1bf  = (unsigned short*)(r0 + 30720000);      // single bf16
    unsigned short* xbf   = h1bf;           // dead before agg1 writes h1bf
    char* p = r0 + 51200000;
    auto alloc = [&](size_t bytes) {
        char* r = p;
        p += (bytes + 255) & ~size_t(255);
        return (void*)r;
    };
    float* dinv    = (float*)alloc(sizeof(float) * N_NODES);
    int* cur_d     = (int*)alloc(sizeof(int) * NUM_DRUGS * STRD);
    int* cur_p     = (int*)alloc(sizeof(int) * N_NODES * STRP);
    int* adj_drug  = (int*)alloc(sizeof(int) * NUM_DRUGS * ELLD);
    int* adj_prot  = (int*)alloc(sizeof(int) * (size_t)N_NODES * ELLP);
    // Region 1 (after reserved extent): buffers the H GEMM reads
    p = (char*)d_ws + ((HRES + 255) & ~size_t(255));
    unsigned short* Gb    = (unsigned short*)alloc(2 * NUM_DRUGS * CDIM);
    unsigned short* wg1Th = (unsigned short*)alloc(2 * CDIM * CDIM);
    unsigned short* wg1Tl = (unsigned short*)alloc(2 * CDIM * CDIM);
    unsigned short* wg2Th = (unsigned short*)alloc(2 * CDIM * CDIM);
    unsigned short* wg2Tl = (unsigned short*)alloc(2 * CDIM * CDIM);
    unsigned short* W1Tb  = (unsigned short*)alloc(2 * (size_t)N_CL * HID * HID);

    // zero counters (fill range in prep_all depends on it in stream order)
    zero_counts<<<(N_NODES + 255) / 256, 256, 0, stream>>>(cur_d, cur_p);
    // fused prep: ELL fill + x bf16 convert + Wg transposes + W1 transpose
    prep_all<<<NB_FILL + NB_T64 + NB_TWG + NB_SPLIT, 256, 0, stream>>>(
        ei, cur_d, adj_drug, cur_p, adj_prot,
        x, xbf, Wg1, Wg2, wg1Th, wg1Tl, wg2Th, wg2Tl, W1, W1Tb);
    // GCN layer 1: A single bf16 (xbf), B split (Wg1) -> 2 MFMA; bf16 output;
    // XCD-paired rows; dinv fused as 79 extra blocks.
    gemm_mfma<64, 128, 2, 0, 1><<<dim3(NB_GNODE + 79, 1), 256, 0, stream>>>(
        xbf, nullptr, wg1Th, wg1Tl, nullptr, t1bf, N_NODES, CDIM, CDIM,
        NB_GNODE, cur_d, cur_p, dinv);
    aggregate1<<<NB_AGG_D + NB_AGG_P, 256, 0, stream>>>(
        t1bf, cur_d, adj_drug, cur_p, adj_prot, dinv, bg1, h1bf);
    // GCN layer 2: A single bf16 (h1bf), B split (Wg2) -> 2 MFMA; bf16 output.
    gemm_mfma<64, 128, 2, 0, 1><<<dim3(NB_GNODE, 1), 256, 0, stream>>>(
        h1bf, nullptr, wg2Th, wg2Tl, nullptr, t2bf, N_NODES, CDIM, CDIM,
        NB_GNODE, nullptr, nullptr, nullptr);
    aggregate2p<<<(N_PROT * 64 + 255) / 256, 256, 0, stream>>>(
        t2bf, cur_p, adj_prot, dinv, bg2, h2bf);
    // pool (bf16 gather, 4 waves/drug) -> single-bf16 graph embeddings
    pool_drugs<<<NUM_DRUGS, 256, 0, stream>>>(h2bf, Gb, cur_d, adj_drug);
    // MLP precompute: Hbf[2048, 8192] = Gb @ W1cat, PURE bf16 (1 MFMA/frag),
    // 32KB LDS dbuf -> 5 blocks/CU at 128^2 intensity; XCD-swizzled grid
    gemm_mfma<128, 128, 1, 0, 0><<<dim3(NUM_DRUGS / 128, HN / 128), 256, 0, stream>>>(
        Gb, nullptr, W1Tb, nullptr, nullptr, Hbf, NUM_DRUGS, CDIM, HN,
        NUM_DRUGS / 128, nullptr, nullptr, nullptr);
    // epilogue: gather 2 Hbf rows per batch row, relu+dot, direct store
    mlp_out<<<(BATCH * 64) / 256, 256, 0, stream>>>(Hbf, ddb, ecl, b1, W2, b2, outp);
}

// Round 13
// 214.954 us; speedup vs baseline: 1.1620x; 1.0558x over previous
//
#include <hip/hip_runtime.h>
#include <hip/hip_bf16.h>

// Problem constants (fixed by reference)
#define N_NODES 20000
#define NUM_DRUGS 2048
#define N_PROT (N_NODES - NUM_DRUGS)
#define NUM_DPI 200000
#define E2 400000          // 2*NUM_DPI directed edges
#define CDIM 256           // IN_C == EMB == 256
#define HID 512
#define N_CL 8
#define BATCH 16384
#define HN 8192            // H cols = 8 experts x 2 halves x 512

#define STRD 32            // drug counter padding (ints) = 1 line per counter
#define STRP 16            // protein counter padding
#define ELLD 192           // drug ELL stride (mean deg 97.7, +9.5 sigma)
#define ELLP 48            // protein ELL stride (mean deg 11.1, +11 sigma)

// fused-prep block ranges
#define NB_FILL 782        // ELL fill: 200000 / 256
#define NB_T64 512         // W1 transpose: 4 x 8 x 16
#define NB_TWG 32          // Wg1/Wg2 transpose: 4 x 4 x 2
#define NB_SPLIT 20000     // x convert: 5.12M / 256

// node-GEMM tiling (BM=64): 313 row tiles; XCD-paired grid of 640 (8 x 80)
#define MT_NODE 313
#define NB_GNODE 640       // 8 XCDs x 80 slots (40 row-panels x 2 col-halves; 14 idle)

// aggregate1 grid split
#define NB_AGG_D NUM_DRUGS              // 1 block per drug (4 waves)
#define NB_AGG_P ((N_PROT + 3) / 4)     // 4 proteins per block (1 wave each)

typedef __attribute__((ext_vector_type(8))) short short8;   // 8 bf16 (MFMA A/B frag)
typedef __attribute__((ext_vector_type(4))) float floatx4;  // MFMA C/D frag

__device__ inline unsigned short f2bf(float f) {
    unsigned u = __float_as_uint(f);
    u += 0x7fff + ((u >> 16) & 1);   // RNE
    return (unsigned short)(u >> 16);
}
__device__ inline float bf2f(unsigned short h) {
    return __uint_as_float((unsigned)h << 16);
}
__device__ inline void gload16(const void* g, void* l) {
    __builtin_amdgcn_global_load_lds(
        (const __attribute__((address_space(1))) void*)g,
        (__attribute__((address_space(3))) void*)l, 16, 0, 0);
}
__device__ inline float4 f4fma(float4 v, float s, float4 a) {
    a.x = fmaf(v.x, s, a.x); a.y = fmaf(v.y, s, a.y);
    a.z = fmaf(v.z, s, a.z); a.w = fmaf(v.w, s, a.w);
    return a;
}
__device__ inline float4 bf4(const unsigned short* p) {
    ushort4 q = *(const ushort4*)p;
    return make_float4(bf2f(q.x), bf2f(q.y), bf2f(q.z), bf2f(q.w));
}

// ---------------------------------------------------------------------------
// counter zeroing (tiny dispatch)
__global__ void zero_counts(int* cur_d, int* cur_p) {
    int i = blockIdx.x * blockDim.x + threadIdx.x;
    if (i < N_NODES) cur_p[i * STRP] = 0;
    if (i < NUM_DRUGS) cur_d[i * STRD] = 0;
}

// ---------------------------------------------------------------------------
// Fused prep: ELL fill | W1 transpose (bf16) | Wg1/Wg2 transpose (bf16) |
// x convert (bf16). All weights/activations now SINGLE bf16 — five
// precision-reduction rounds left absmax pinned at 1 output ulp (2.44e-4),
// so the remaining channels are attenuation-dominated.
__global__ __launch_bounds__(256) void prep_all(
        const int* __restrict__ ei, int* __restrict__ cur_d,
        int* __restrict__ adj_drug, int* __restrict__ cur_p,
        int* __restrict__ adj_prot,
        const float* __restrict__ x, unsigned short* __restrict__ xbf,
        const float* __restrict__ Wg1, const float* __restrict__ Wg2,
        unsigned short* __restrict__ wg1Tb, unsigned short* __restrict__ wg2Tb,
        const float* __restrict__ W1, unsigned short* __restrict__ W1Tb) {
    __shared__ float ld[64 * 65];
    int b = blockIdx.x;
    int t = threadIdx.x;
    int tx = t & 63, ty = t >> 6;
    if (b < NB_FILL) {
        int e = b * 256 + t;
        if (e < NUM_DPI) {
            int d = ei[e];
            int p = ei[E2 + e];
            int posd = atomicAdd(&cur_d[d * STRD], 1);
            int posp = atomicAdd(&cur_p[p * STRP], 1);
            if (posd < ELLD) adj_drug[d * ELLD + posd] = p;   // clamp
            if (posp < ELLP) adj_prot[(size_t)p * ELLP + posp] = d;
        }
        return;
    }
    b -= NB_FILL;
    if (b < NB_T64) {
        // W1 [16 slabs][256][512] -> W1cat^T [8192][256] single bf16
        int m = b >> 5;
        int k0 = (b & 3) * 64, n0 = ((b >> 2) & 7) * 64;
        const float* Wm = W1 + (size_t)m * CDIM * HID;
#pragma unroll
        for (int rr = 0; rr < 16; rr++) {
            int kl = rr * 4 + ty;
            ld[tx * 65 + kl] = Wm[(size_t)(k0 + kl) * HID + n0 + tx];
        }
        __syncthreads();
        size_t obase = (size_t)m * HID * CDIM;
#pragma unroll
        for (int rr = 0; rr < 16; rr++) {
            int nl = rr * 4 + ty;
            size_t o = obase + (size_t)(n0 + nl) * CDIM + k0 + tx;
            W1Tb[o] = f2bf(ld[nl * 65 + tx]);
        }
        return;
    }
    b -= NB_T64;
    if (b < NB_TWG) {
        // Wg1/Wg2 [256][256] -> transposed single bf16
        const float* W = (b >> 4) ? Wg2 : Wg1;
        unsigned short* ob = (b >> 4) ? wg2Tb : wg1Tb;
        int k0 = (b & 3) * 64, n0 = ((b >> 2) & 3) * 64;
#pragma unroll
        for (int rr = 0; rr < 16; rr++) {
            int kl = rr * 4 + ty;
            ld[tx * 65 + kl] = W[(size_t)(k0 + kl) * CDIM + n0 + tx];
        }
        __syncthreads();
#pragma unroll
        for (int rr = 0; rr < 16; rr++) {
            int nl = rr * 4 + ty;
            size_t o = (size_t)(n0 + nl) * CDIM + k0 + tx;
            ob[o] = f2bf(ld[nl * 65 + tx]);
        }
        return;
    }
    b -= NB_TWG;
    {   // x convert: exactly NB_SPLIT blocks cover 5.12M elems (single bf16)
        int i = b * 256 + t;
        xbf[i] = f2bf(x[i]);
    }
}

// ---------------------------------------------------------------------------
// Pure-bf16 MFMA GEMM: C[M,N] = A[M,K] @ B[K,N], B passed as B^T ([N][K]).
// All operands single bf16 -> 1 MFMA per fragment pair.
//   node GEMMs <64,128,SWZ2>: 24KB LDS dbuf -> 6 blocks/CU.
//   H GEMM <128,128,SWZ1>: 32KB LDS dbuf -> 5 blocks/CU at 128^2 intensity.
// SWZ=1: XCD k owns col-tiles [8k,8k+8) of the (16,64) grid.
// SWZ=2: XCD-paired rows on (640,1): xcd=id&7, k=id>>3, by=k&1,
//   bx=xcd*40+(k>>1); bx>=313 idle. Bijective onto [0,313)x[0,2).
// Blocks with blockIdx.x >= mTiles run the fused dinv computation instead.
template <int BM, int BN, int SWZ>
__global__ __launch_bounds__(256) void gemm_mfma(
        const unsigned short* __restrict__ A,
        const unsigned short* __restrict__ BT,
        unsigned short* __restrict__ Cbf,
        int M, int K, int N, int mTiles,
        const int* __restrict__ cur_d, const int* __restrict__ cur_p,
        float* __restrict__ dinv) {
    if ((int)blockIdx.x >= mTiles) {
        int i = (((int)blockIdx.x - mTiles) * (int)gridDim.y + (int)blockIdx.y) * 256
                + (int)threadIdx.x;
        if (i < N_NODES) {
            int deg = (i < NUM_DRUGS) ? cur_d[i * STRD] : cur_p[i * STRP];
            dinv[i] = rsqrtf((float)(deg + 1));
        }
        return;
    }
    constexpr int MI = BM / 32;           // acc row-frags per wave
    constexpr int NJ = BN / 32;           // acc col-frags per wave
    __shared__ unsigned short sA[2][BM * 32];
    __shared__ unsigned short sB[2][BN * 32];
    int t = threadIdx.x;
    int wv = t >> 6, lane = t & 63, quad = lane >> 4, l15 = lane & 15;
    int bx = blockIdx.x, by = blockIdx.y;
    if constexpr (SWZ == 1) {
        int w = by * 16 + bx;
        int xcd = w & 7, j = w >> 3;
        bx = j & 15;
        by = xcd * 8 + (j >> 4);
    }
    if constexpr (SWZ == 2) {
        int id = bx;
        int xcd = id & 7, k = id >> 3;    // k in [0,80)
        by = k & 1;
        bx = xcd * 40 + (k >> 1);
        if (bx >= MT_NODE) return;        // 14 idle pad blocks
    }
    int m0 = bx * BM, n0 = by * BN;
    int m0w = (wv >> 1) * (BM / 2), n0w = (wv & 1) * (BN / 2);
    floatx4 zero = {0.f, 0.f, 0.f, 0.f};
    floatx4 acc[MI][NJ];
#pragma unroll
    for (int i = 0; i < MI; i++)
#pragma unroll
        for (int j = 0; j < NJ; j++) acc[i][j] = zero;

    auto STAGE = [&](int buf, int kk) {
#pragma unroll
        for (int s = t; s < BM * 4; s += 256) {   // A slots
            int row = s >> 2, pos = s & 3;
            int ch = pos ^ ((row >> 1) & 3);      // XOR-swizzled chunk
            int arow = m0 + row; if (arow > M - 1) arow = M - 1;
            gload16(A + (size_t)arow * K + kk + ch * 8, &sA[buf][s * 8]);
        }
#pragma unroll
        for (int s = t; s < BN * 4; s += 256) {   // B slots
            int row = s >> 2, pos = s & 3;
            int ch = pos ^ ((row >> 1) & 3);
            int brow = n0 + row; if (brow > N - 1) brow = N - 1;
            gload16(BT + (size_t)brow * K + kk + ch * 8, &sB[buf][s * 8]);
        }
    };

    int nk = K >> 5;
    STAGE(0, 0);
    asm volatile("s_waitcnt vmcnt(0)" ::: "memory");
    __builtin_amdgcn_s_barrier();
    int cur = 0;
    for (int it = 0; it < nk; ++it) {
        if (it + 1 < nk) STAGE(cur ^ 1, (it + 1) << 5);   // prefetch next tile
        short8 af[MI], bf[NJ];
        int posq = quad ^ ((l15 >> 1) & 3);
#pragma unroll
        for (int i = 0; i < MI; i++) {
            int sl = (m0w + i * 16 + l15) * 4 + posq;
            af[i] = *(const short8*)&sA[cur][sl * 8];
        }
#pragma unroll
        for (int j = 0; j < NJ; j++) {
            int sl = (n0w + j * 16 + l15) * 4 + posq;
            bf[j] = *(const short8*)&sB[cur][sl * 8];
        }
#pragma unroll
        for (int i = 0; i < MI; i++)
#pragma unroll
            for (int j = 0; j < NJ; j++)
                acc[i][j] = __builtin_amdgcn_mfma_f32_16x16x32_bf16(af[i], bf[j], acc[i][j], 0, 0, 0);
        if (it + 1 < nk) {
            asm volatile("s_waitcnt vmcnt(0)" ::: "memory");  // next tile landed
            __builtin_amdgcn_s_barrier();                     // all reads of cur done
            cur ^= 1;
        }
    }
#pragma unroll
    for (int i = 0; i < MI; i++) {
        int gr = m0 + m0w + i * 16 + quad * 4;
#pragma unroll
        for (int r = 0; r < 4; r++) {
            if (gr + r < M) {
#pragma unroll
                for (int j = 0; j < NJ; j++) {
                    size_t o = (size_t)(gr + r) * N + n0 + n0w + j * 16 + l15;
                    Cbf[o] = f2bf(acc[i][j][r]);
                }
            }
        }
    }
}

// ---------------------------------------------------------------------------
// Layer-1 GCN aggregate — reads bf16 (t1bf), writes h1 single bf16.
__global__ __launch_bounds__(256) void aggregate1(const unsigned short* __restrict__ tmpbf,
                                                  const int* __restrict__ cur_d,
                                                  const int* __restrict__ adj_drug,
                                                  const int* __restrict__ cur_p,
                                                  const int* __restrict__ adj_prot,
                                                  const float* __restrict__ dinv,
                                                  const float* __restrict__ bias,
                                                  unsigned short* __restrict__ outbf) {
    __shared__ float4 red[4][64];
    int b = blockIdx.x;
    int lane = threadIdx.x & 63;
    if (b < NB_AGG_D) {
        int d = b;
        int w = threadIdx.x >> 6;
        const int* adj = adj_drug + (size_t)d * ELLD;
        int ecnt = cur_d[d * STRD];
        int e = ecnt < ELLD ? ecnt : ELLD;
        float4 a0 = make_float4(0.f, 0.f, 0.f, 0.f);
        float4 a1 = a0, a2 = a0, a3 = a0;
        int idx = w;
        for (; idx + 12 < e; idx += 16) {
            int j0 = adj[idx], j1 = adj[idx + 4], j2 = adj[idx + 8], j3 = adj[idx + 12];
            float d0 = dinv[j0], d1 = dinv[j1], d2 = dinv[j2], d3 = dinv[j3];
            float4 v0 = bf4(&tmpbf[(size_t)j0 * CDIM + lane * 4]);
            float4 v1 = bf4(&tmpbf[(size_t)j1 * CDIM + lane * 4]);
            float4 v2 = bf4(&tmpbf[(size_t)j2 * CDIM + lane * 4]);
            float4 v3 = bf4(&tmpbf[(size_t)j3 * CDIM + lane * 4]);
            a0 = f4fma(v0, d0, a0);
            a1 = f4fma(v1, d1, a1);
            a2 = f4fma(v2, d2, a2);
            a3 = f4fma(v3, d3, a3);
        }
        for (; idx < e; idx += 4) {
            int j = adj[idx];
            a0 = f4fma(bf4(&tmpbf[(size_t)j * CDIM + lane * 4]), dinv[j], a0);
        }
        a0.x = (a0.x + a1.x) + (a2.x + a3.x);
        a0.y = (a0.y + a1.y) + (a2.y + a3.y);
        a0.z = (a0.z + a1.z) + (a2.z + a3.z);
        a0.w = (a0.w + a1.w) + (a2.w + a3.w);
        red[w][lane] = a0;
        __syncthreads();
        if (w == 0) {
            float di = dinv[d];
            float4 r0 = red[0][lane], r1 = red[1][lane], r2 = red[2][lane], r3 = red[3][lane];
            float4 self = bf4(&tmpbf[(size_t)d * CDIM + lane * 4]);
            float4 acc;
            acc.x = (r0.x + r1.x) + (r2.x + r3.x) + self.x * di;
            acc.y = (r0.y + r1.y) + (r2.y + r3.y) + self.y * di;
            acc.z = (r0.z + r1.z) + (r2.z + r3.z) + self.z * di;
            acc.w = (r0.w + r1.w) + (r2.w + r3.w) + self.w * di;
            float4 bv = ((const float4*)bias)[lane];
            ushort4 o;
            o.x = f2bf(fmaxf(fmaf(acc.x, di, bv.x), 0.f));
            o.y = f2bf(fmaxf(fmaf(acc.y, di, bv.y), 0.f));
            o.z = f2bf(fmaxf(fmaf(acc.z, di, bv.z), 0.f));
            o.w = f2bf(fmaxf(fmaf(acc.w, di, bv.w), 0.f));
            *(ushort4*)&outbf[(size_t)d * CDIM + lane * 4] = o;
        }
        return;
    }
    // protein destinations: one wave per node, bf16 gathers
    int i = NUM_DRUGS + (b - NB_AGG_D) * 4 + (threadIdx.x >> 6);
    if (i >= N_NODES) return;
    float di = dinv[i];
    float4 a0 = make_float4(0.f, 0.f, 0.f, 0.f);
    float4 a1 = a0, a2 = a0, a3 = a0;
    const int* adj = adj_prot + (size_t)i * ELLP;
    int e = cur_p[i * STRP];
    int idx = 0;
    for (; idx + 4 <= e; idx += 4) {
        int j0 = adj[idx + 0], j1 = adj[idx + 1];
        int j2 = adj[idx + 2], j3 = adj[idx + 3];
        float d0 = dinv[j0], d1 = dinv[j1], d2 = dinv[j2], d3 = dinv[j3];
        float4 v0 = bf4(&tmpbf[(size_t)j0 * CDIM + lane * 4]);
        float4 v1 = bf4(&tmpbf[(size_t)j1 * CDIM + lane * 4]);
        float4 v2 = bf4(&tmpbf[(size_t)j2 * CDIM + lane * 4]);
        float4 v3 = bf4(&tmpbf[(size_t)j3 * CDIM + lane * 4]);
        a0 = f4fma(v0, d0, a0);
        a1 = f4fma(v1, d1, a1);
        a2 = f4fma(v2, d2, a2);
        a3 = f4fma(v3, d3, a3);
    }
    for (; idx < e; idx++) {
        int j = adj[idx];
        a0 = f4fma(bf4(&tmpbf[(size_t)j * CDIM + lane * 4]), dinv[j], a0);
    }
    float4 self = bf4(&tmpbf[(size_t)i * CDIM + lane * 4]);
    float4 acc;
    acc.x = (a0.x + a1.x) + (a2.x + a3.x) + self.x * di;
    acc.y = (a0.y + a1.y) + (a2.y + a3.y) + self.y * di;
    acc.z = (a0.z + a1.z) + (a2.z + a3.z) + self.z * di;
    acc.w = (a0.w + a1.w) + (a2.w + a3.w) + self.w * di;
    float4 bv = ((const float4*)bias)[lane];
    ushort4 o;
    o.x = f2bf(fmaxf(fmaf(acc.x, di, bv.x), 0.f));
    o.y = f2bf(fmaxf(fmaf(acc.y, di, bv.y), 0.f));
    o.z = f2bf(fmaxf(fmaf(acc.z, di, bv.z), 0.f));
    o.w = f2bf(fmaxf(fmaf(acc.w, di, bv.w), 0.f));
    *(ushort4*)&outbf[(size_t)i * CDIM + lane * 4] = o;
}

// Layer-2 GCN aggregate, PROTEIN rows only, bf16 gathers (t2bf).
__global__ __launch_bounds__(256) void aggregate2p(const unsigned short* __restrict__ t2bf,
                                                   const int* __restrict__ cur_p,
                                                   const int* __restrict__ adj_prot,
                                                   const float* __restrict__ dinv,
                                                   const float* __restrict__ bias,
                                                   unsigned short* __restrict__ h2bf) {
    int w = (blockIdx.x * blockDim.x + threadIdx.x) >> 6;
    int lane = threadIdx.x & 63;
    if (w >= N_PROT) return;
    int i = NUM_DRUGS + w;
    float di = dinv[i];
    float4 a0 = make_float4(0.f, 0.f, 0.f, 0.f);
    float4 a1 = a0, a2 = a0, a3 = a0;
    const int* adj = adj_prot + (size_t)i * ELLP;
    int e = cur_p[i * STRP];
    int idx = 0;
    for (; idx + 4 <= e; idx += 4) {
        int j0 = adj[idx + 0], j1 = adj[idx + 1];
        int j2 = adj[idx + 2], j3 = adj[idx + 3];
        float d0 = dinv[j0], d1 = dinv[j1], d2 = dinv[j2], d3 = dinv[j3];
        float4 v0 = bf4(&t2bf[(size_t)j0 * CDIM + lane * 4]);
        float4 v1 = bf4(&t2bf[(size_t)j1 * CDIM + lane * 4]);
        float4 v2 = bf4(&t2bf[(size_t)j2 * CDIM + lane * 4]);
        float4 v3 = bf4(&t2bf[(size_t)j3 * CDIM + lane * 4]);
        a0 = f4fma(v0, d0, a0);
        a1 = f4fma(v1, d1, a1);
        a2 = f4fma(v2, d2, a2);
        a3 = f4fma(v3, d3, a3);
    }
    for (; idx < e; idx++) {
        int j = adj[idx];
        a0 = f4fma(bf4(&t2bf[(size_t)j * CDIM + lane * 4]), dinv[j], a0);
    }
    float4 self = bf4(&t2bf[(size_t)i * CDIM + lane * 4]);
    float4 acc;
    acc.x = (a0.x + a1.x) + (a2.x + a3.x) + self.x * di;
    acc.y = (a0.y + a1.y) + (a2.y + a3.y) + self.y * di;
    acc.z = (a0.z + a1.z) + (a2.z + a3.z) + self.z * di;
    acc.w = (a0.w + a1.w) + (a2.w + a3.w) + self.w * di;
    float4 bv = ((const float4*)bias)[lane];
    ushort4 o;
    o.x = f2bf(fmaxf(fmaf(acc.x, di, bv.x), 0.f));
    o.y = f2bf(fmaxf(fmaf(acc.y, di, bv.y), 0.f));
    o.z = f2bf(fmaxf(fmaf(acc.z, di, bv.z), 0.f));
    o.w = f2bf(fmaxf(fmaf(acc.w, di, bv.w), 0.f));
    *(ushort4*)&h2bf[(size_t)i * CDIM + lane * 4] = o;
}

// scatter-mean pool from bf16 h2 -> single bf16 graph embeddings.
__global__ __launch_bounds__(256) void pool_drugs(const unsigned short* __restrict__ h2bf,
                                                  unsigned short* __restrict__ Gb,
                                                  const int* __restrict__ cur_d,
                                                  const int* __restrict__ adj_drug) {
    __shared__ float4 red[4][64];
    int d = blockIdx.x;
    int w = threadIdx.x >> 6, lane = threadIdx.x & 63;
    const int* adj = adj_drug + (size_t)d * ELLD;
    int ecnt = cur_d[d * STRD];
    int e = ecnt < ELLD ? ecnt : ELLD;
    float4 a0 = make_float4(0.f, 0.f, 0.f, 0.f);
    float4 a1 = a0, a2 = a0, a3 = a0;
    int idx = w;
    for (; idx + 12 < e; idx += 16) {
        int j0 = adj[idx], j1 = adj[idx + 4], j2 = adj[idx + 8], j3 = adj[idx + 12];
        float4 v0 = bf4(&h2bf[(size_t)j0 * CDIM + lane * 4]);
        float4 v1 = bf4(&h2bf[(size_t)j1 * CDIM + lane * 4]);
        float4 v2 = bf4(&h2bf[(size_t)j2 * CDIM + lane * 4]);
        float4 v3 = bf4(&h2bf[(size_t)j3 * CDIM + lane * 4]);
        a0.x += v0.x; a0.y += v0.y; a0.z += v0.z; a0.w += v0.w;
        a1.x += v1.x; a1.y += v1.y; a1.z += v1.z; a1.w += v1.w;
        a2.x += v2.x; a2.y += v2.y; a2.z += v2.z; a2.w += v2.w;
        a3.x += v3.x; a3.y += v3.y; a3.z += v3.z; a3.w += v3.w;
    }
    for (; idx < e; idx += 4) {
        float4 v = bf4(&h2bf[(size_t)adj[idx] * CDIM + lane * 4]);
        a0.x += v.x; a0.y += v.y; a0.z += v.z; a0.w += v.w;
    }
    a0.x = (a0.x + a1.x) + (a2.x + a3.x);
    a0.y = (a0.y + a1.y) + (a2.y + a3.y);
    a0.z = (a0.z + a1.z) + (a2.z + a3.z);
    a0.w = (a0.w + a1.w) + (a2.w + a3.w);
    red[w][lane] = a0;
    __syncthreads();
    if (w == 0) {
        float4 r0 = red[0][lane], r1 = red[1][lane], r2 = red[2][lane], r3 = red[3][lane];
        float4 acc;
        acc.x = (r0.x + r1.x) + (r2.x + r3.x);
        acc.y = (r0.y + r1.y) + (r2.y + r3.y);
        acc.z = (r0.z + r1.z) + (r2.z + r3.z);
        acc.w = (r0.w + r1.w) + (r2.w + r3.w);
        float sc = 1.f / (float)(ecnt > 1 ? ecnt : 1);
        ushort4 o;
        o.x = f2bf(acc.x * sc);
        o.y = f2bf(acc.y * sc);
        o.z = f2bf(acc.z * sc);
        o.w = f2bf(acc.w * sc);
        *(ushort4*)&Gb[(size_t)d * CDIM + lane * 4] = o;
    }
}

// ---------------------------------------------------------------------------
// MLP epilogue: out[r] = sum_n relu(H[d0][2c*512+n] + H[d1][(2c+1)*512+n]
//                                   + b1[c][n]) * W2[c][n] + b2[c]
__global__ __launch_bounds__(256) void mlp_out(const unsigned short* __restrict__ Hbf,
                                               const int* __restrict__ ddb,
                                               const int* __restrict__ ecl,
                                               const float* __restrict__ b1,
                                               const float* __restrict__ W2,
                                               const float* __restrict__ b2,
                                               float* __restrict__ outp) {
    int r = (blockIdx.x * blockDim.x + threadIdx.x) >> 6;
    int lane = threadIdx.x & 63;
    if (r >= BATCH) return;
    int c = ecl[r];
    int d0 = ddb[r], d1 = ddb[BATCH + r];
    int n = lane * 8;
    const unsigned short* h0 = Hbf + (size_t)d0 * HN + (size_t)(c * 2) * HID + n;
    const unsigned short* h1 = Hbf + (size_t)d1 * HN + (size_t)(c * 2 + 1) * HID + n;
    const float* b1e = b1 + (size_t)c * HID + n;
    const float* w2e = W2 + (size_t)c * HID + n;
    short8 a8 = *(const short8*)h0;
    short8 b8 = *(const short8*)h1;
    float4 bb0 = *(const float4*)(b1e);
    float4 bb1 = *(const float4*)(b1e + 4);
    float4 w0 = *(const float4*)(w2e);
    float4 w1 = *(const float4*)(w2e + 4);
    float s = 0.f;
    float h;
    h = bf2f((unsigned short)a8[0]) + bf2f((unsigned short)b8[0]) + bb0.x;
    s = fmaf(fmaxf(h, 0.f), w0.x, s);
    h = bf2f((unsigned short)a8[1]) + bf2f((unsigned short)b8[1]) + bb0.y;
    s = fmaf(fmaxf(h, 0.f), w0.y, s);
    h = bf2f((unsigned short)a8[2]) + bf2f((unsigned short)b8[2]) + bb0.z;
    s = fmaf(fmaxf(h, 0.f), w0.z, s);
    h = bf2f((unsigned short)a8[3]) + bf2f((unsigned short)b8[3]) + bb0.w;
    s = fmaf(fmaxf(h, 0.f), w0.w, s);
    h = bf2f((unsigned short)a8[4]) + bf2f((unsigned short)b8[4]) + bb1.x;
    s = fmaf(fmaxf(h, 0.f), w1.x, s);
    h = bf2f((unsigned short)a8[5]) + bf2f((unsigned short)b8[5]) + bb1.y;
    s = fmaf(fmaxf(h, 0.f), w1.y, s);
    h = bf2f((unsigned short)a8[6]) + bf2f((unsigned short)b8[6]) + bb1.z;
    s = fmaf(fmaxf(h, 0.f), w1.z, s);
    h = bf2f((unsigned short)a8[7]) + bf2f((unsigned short)b8[7]) + bb1.w;
    s = fmaf(fmaxf(h, 0.f), w1.w, s);
    s += __shfl_xor(s, 1);
    s += __shfl_xor(s, 2);
    s += __shfl_xor(s, 4);
    s += __shfl_xor(s, 8);
    s += __shfl_xor(s, 16);
    s += __shfl_xor(s, 32);
    if (lane == 0) outp[r] = s + b2[c];
}

// ---------------------------------------------------------------------------
extern "C" void kernel_launch(void* const* d_in, const int* in_sizes, int n_in,
                              void* d_out, int out_size, void* d_ws, size_t ws_size,
                              hipStream_t stream) {
    const float* x   = (const float*)d_in[0];
    const int* ei    = (const int*)d_in[1];
    const int* ddb   = (const int*)d_in[2];
    const int* ecl   = (const int*)d_in[3];
    const float* Wg1 = (const float*)d_in[5];
    const float* bg1 = (const float*)d_in[6];
    const float* Wg2 = (const float*)d_in[7];
    const float* bg2 = (const float*)d_in[8];
    const float* W1  = (const float*)d_in[9];
    const float* b1  = (const float*)d_in[10];
    const float* W2  = (const float*)d_in[11];
    const float* b2  = (const float*)d_in[12];
    float* outp = (float*)d_out;

    const size_t HRES = (size_t)NUM_DRUGS * HN * sizeof(float);    // 67.1 MB reserved
    // Region 0 (inside reserved extent; all dead before the H GEMM writes Hbf):
    // Hbf (bf16, 33.6 MB) overlaps t2bf/t1bf/h1bf/xbf — all dead at H-GEMM time.
    char* r0 = (char*)d_ws;
    unsigned short* Hbf   = (unsigned short*)d_ws;
    unsigned short* t2bf  = (unsigned short*)r0;                   // 10.24 MB
    unsigned short* t1bf  = (unsigned short*)(r0 + 20480000);
    unsigned short* h2bf  = t1bf;
    unsigned short* h1bf  = (unsigned short*)(r0 + 30720000);      // single bf16
    unsigned short* xbf   = h1bf;           // dead before agg1 writes h1bf
    char* p = r0 + 51200000;
    auto alloc = [&](size_t bytes) {
        char* r = p;
        p += (bytes + 255) & ~size_t(255);
        return (void*)r;
    };
    float* dinv    = (float*)alloc(sizeof(float) * N_NODES);
    int* cur_d     = (int*)alloc(sizeof(int) * NUM_DRUGS * STRD);
    int* cur_p     = (int*)alloc(sizeof(int) * N_NODES * STRP);
    int* adj_drug  = (int*)alloc(sizeof(int) * NUM_DRUGS * ELLD);
    int* adj_prot  = (int*)alloc(sizeof(int) * (size_t)N_NODES * ELLP);
    // Region 1 (after reserved extent): buffers the H GEMM reads
    p = (char*)d_ws + ((HRES + 255) & ~size_t(255));
    unsigned short* Gb    = (unsigned short*)alloc(2 * NUM_DRUGS * CDIM);
    unsigned short* wg1Tb = (unsigned short*)alloc(2 * CDIM * CDIM);
    unsigned short* wg2Tb = (unsigned short*)alloc(2 * CDIM * CDIM);
    unsigned short* W1Tb  = (unsigned short*)alloc(2 * (size_t)N_CL * HID * HID);

    // zero counters (fill range in prep_all depends on it in stream order)
    zero_counts<<<(N_NODES + 255) / 256, 256, 0, stream>>>(cur_d, cur_p);
    // fused prep: ELL fill + x bf16 convert + Wg transposes + W1 transpose
    prep_all<<<NB_FILL + NB_T64 + NB_TWG + NB_SPLIT, 256, 0, stream>>>(
        ei, cur_d, adj_drug, cur_p, adj_prot,
        x, xbf, Wg1, Wg2, wg1Tb, wg2Tb, W1, W1Tb);
    // GCN layer 1: pure bf16 (1 MFMA), 24KB LDS -> 6 blocks/CU; XCD-paired
    // rows; dinv fused as 79 extra blocks.
    gemm_mfma<64, 128, 2><<<dim3(NB_GNODE + 79, 1), 256, 0, stream>>>(
        xbf, wg1Tb, t1bf, N_NODES, CDIM, CDIM,
        NB_GNODE, cur_d, cur_p, dinv);
    aggregate1<<<NB_AGG_D + NB_AGG_P, 256, 0, stream>>>(
        t1bf, cur_d, adj_drug, cur_p, adj_prot, dinv, bg1, h1bf);
    // GCN layer 2: pure bf16.
    gemm_mfma<64, 128, 2><<<dim3(NB_GNODE, 1), 256, 0, stream>>>(
        h1bf, wg2Tb, t2bf, N_NODES, CDIM, CDIM,
        NB_GNODE, nullptr, nullptr, nullptr);
    aggregate2p<<<(N_PROT * 64 + 255) / 256, 256, 0, stream>>>(
        t2bf, cur_p, adj_prot, dinv, bg2, h2bf);
    // pool (bf16 gather, 4 waves/drug) -> single-bf16 graph embeddings
    pool_drugs<<<NUM_DRUGS, 256, 0, stream>>>(h2bf, Gb, cur_d, adj_drug);
    // MLP precompute: Hbf[2048, 8192] = Gb @ W1cat, pure bf16,
    // 32KB LDS dbuf -> 5 blocks/CU; XCD-swizzled (16,64) grid
    gemm_mfma<128, 128, 1><<<dim3(NUM_DRUGS / 128, HN / 128), 256, 0, stream>>>(
        Gb, W1Tb, Hbf, NUM_DRUGS, CDIM, HN,
        NUM_DRUGS / 128, nullptr, nullptr, nullptr);
    // epilogue: gather 2 Hbf rows per batch row, relu+dot, direct store
    mlp_out<<<(BATCH * 64) / 256, 256, 0, stream>>>(Hbf, ddb, ecl, b1, W2, b2, outp);
}